// Round 11
// baseline (232.215 us; speedup 1.0000x reference)
//
#include <hip/hip_runtime.h>
#include <hip/hip_fp16.h>

#define OUTD 7
#define PD 14             // 14 sample coords per axis
#define NCH 256

// ---- transposed buffer layout (HALF-element offsets), [lvl][img][P][C] ----
#define TOFF0 0
#define TOFF1 20480000    // + 2*40000*256
#define TOFF2 25600000    // + 2*10000*256
#define TOFF3 26880000    // + 2*2500*256
#define TTOT  27200000    // halfs (= 54.4 MB)
#define TBASE_BYTES 16384

// transpose tiling: 32 p-rows x 256 channels per block, 256 threads.
// p-tiles/lvl: 1250, 313, 79, 20 -> 1662/img -> 3324 transpose blocks + 1 sort
#define NTILES_IMG 1662
#define NB_TRANS   3324

__device__ __forceinline__ unsigned int roi_key(const float* boxes,
                                                const int* img_ids, int e, int N)
{
    unsigned int key = 0xFFFFFFFFu;
    if (e < N) {
        const float bx1 = boxes[e * 4 + 0];
        const float by1 = boxes[e * 4 + 1];
        const float bx2 = boxes[e * 4 + 2];
        const float by2 = boxes[e * 4 + 3];
        const float area = (bx2 - bx1) * (by2 - by1);
        const float s = sqrtf(area);
        float lvlf = floorf(4.0f + log2f(s / 224.0f + 1e-6f));
        lvlf = fminf(fmaxf(lvlf, 2.0f), 5.0f);
        const int lvl = (int)lvlf - 2;
        const float scales[4] = {0.25f, 0.125f, 0.0625f, 0.03125f};
        const float sc = scales[lvl];
        int cx = (int)(0.5f * (bx1 + bx2) * sc);
        int cy = (int)(0.5f * (by1 + by2) * sc);
        cx = min(max(cx, 0), 127);
        cy = min(max(cy, 0), 127);
        unsigned int m = 0;
#pragma unroll
        for (int b = 0; b < 7; ++b)
            m |= ((cy >> b) & 1u) << (2 * b + 1) | ((cx >> b) & 1u) << (2 * b);
        key = ((((unsigned)lvl << 1) | (unsigned)img_ids[e]) << 14) | m;
    }
    return key;
}

// ---------------- fused prep: transpose blocks + 1 sort block ----------------
// Round-10 lesson: transpose at 2.1 TB/s HBM, 3.0 TB/s effective -> NOT
// BW-bound; granularity >=256B proven irrelevant (r9). Suspects: 2-block/CU
// phase serialization + serial 1-CU sort. Fix: 32-row tile (33.3KB LDS ->
// 4 blocks/CU, phase mixing) + sort fused as an extra block (rides free).
__global__ __launch_bounds__(256)
void prep_kernel(const float* __restrict__ f0, const float* __restrict__ f1,
                 const float* __restrict__ f2, const float* __restrict__ f3,
                 const float* __restrict__ boxes,
                 const int*   __restrict__ img_ids,
                 int* __restrict__ order,
                 __half* __restrict__ T, int N)
{
    __shared__ __align__(16) float smbuf[32 * 260];   // 33280 B
    const int t = threadIdx.x;

    if (blockIdx.x == NB_TRANS) {
        // ==== sort path: bitonic over 1024 slots, 4 elems/thread ====
        unsigned long long* kv = (unsigned long long*)smbuf;
        for (int e = t; e < 1024; e += 256)
            kv[e] = ((unsigned long long)roi_key(boxes, img_ids, e, N) << 32)
                    | (unsigned)e;
        __syncthreads();
        for (int k = 2; k <= 1024; k <<= 1) {
            for (int j = k >> 1; j > 0; j >>= 1) {
                for (int i = t; i < 1024; i += 256) {
                    const int ixj = i ^ j;
                    if (ixj > i) {
                        const bool up = ((i & k) == 0);
                        const unsigned long long a = kv[i], b = kv[ixj];
                        if ((a > b) == up) { kv[i] = b; kv[ixj] = a; }
                    }
                }
                __syncthreads();
            }
        }
        for (int e = t; e < 1024; e += 256)
            if (e < N) order[e] = (int)(kv[e] & 0xFFFFFFFFu);
        return;
    }

    // ==== transpose path: [C][H][W] f32 -> [P][C] f16, 32p x 256c tile ====
    int id = blockIdx.x;                          // 0..3323
    const int img = (id >= NTILES_IMG) ? 1 : 0; if (img) id -= NTILES_IMG;
    int lvl, pt;
    if (id < 1250)      { lvl = 0; pt = id; }
    else if (id < 1563) { lvl = 1; pt = id - 1250; }
    else if (id < 1642) { lvl = 2; pt = id - 1563; }
    else                { lvl = 3; pt = id - 1642; }

    const int  Ps[4]   = {40000, 10000, 2500, 625};
    const long TO[4]   = {TOFF0, TOFF1, TOFF2, TOFF3};
    const float* feats[4] = {f0, f1, f2, f3};
    const int P = Ps[lvl];
    const float* __restrict__ src = feats[lvl] + (size_t)img * NCH * (size_t)P;
    __half* __restrict__ dst = T + TO[lvl] + (size_t)img * (size_t)P * NCH;
    const int p0 = pt * 32;

    float (*tile)[260] = (float (*)[260])smbuf;   // stride 260 (1040B, 16B-aligned)

    // ---- phase 1: 8 x (coalesced float4 along P), scalar LDS scatter ----
    const int a   = t & 7;            // p4-group 0..7
    const int cg0 = t >> 3;           // 0..31
    const int p4  = a * 4;

#pragma unroll
    for (int i = 0; i < 8; ++i) {
        const int cs = cg0 + 32 * i;  // 0..255
        const float* sp = src + (size_t)cs * P + p0;
        float4 v;
        if (((P & 3) == 0) && (p0 + p4 + 3 < P)) {
            v = *(const float4*)(sp + p4);       // coalesced 16B, aligned
        } else {
            const int m = P - 1 - p0;            // clamp (edge tile / P=625)
            v.x = sp[min(p4 + 0, m)]; v.y = sp[min(p4 + 1, m)];
            v.z = sp[min(p4 + 2, m)]; v.w = sp[min(p4 + 3, m)];
        }
        tile[p4 + 0][cs] = v.x;
        tile[p4 + 1][cs] = v.y;
        tile[p4 + 2][cs] = v.z;
        tile[p4 + 3][cs] = v.w;
    }
    __syncthreads();

    // ---- phase 2: cvt fp16, write full [P][C] rows (512B/wave-instr) ----
    const int c4 = (t & 63) * 4;
    const int w  = t >> 6;            // 0..3
#pragma unroll
    for (int i = 0; i < 8; ++i) {
        const int p = w + 4 * i;      // 0..31
        if (p0 + p < P) {
            const __half2 h0 = __floats2half2_rn(tile[p][c4 + 0], tile[p][c4 + 1]);
            const __half2 h1 = __floats2half2_rn(tile[p][c4 + 2], tile[p][c4 + 3]);
            uint2 o;
            o.x = *(const unsigned int*)&h0;
            o.y = *(const unsigned int*)&h1;
            *(uint2*)(dst + (size_t)(p0 + p) * NCH + c4) = o;   // 8B aligned
        }
    }
}

// ---------------- pooler on transposed fp16 layout (r10: ~33us) ----------------
// Block = 1 ROI, 256 threads = 4 waves. Lane owns channels 4l..4l+3 (8B/lane,
// dwordx2): every tap load = 64 lanes x 8B = 512B contiguous, fully coalesced.
__global__ __launch_bounds__(256)
void pooler_t_kernel(const __half* __restrict__ T,
                     const float* __restrict__ boxes,
                     const int*   __restrict__ img_ids,
                     const int*   __restrict__ order,
                     float* __restrict__ out, int N)
{
    int bx = blockIdx.x;
    int sidx;
    if ((N & 7) == 0) sidx = (bx & 7) * (N >> 3) + (bx >> 3);  // XCD-contiguous
    else              sidx = bx;
    const int roi = order[sidx];
    const int t = threadIdx.x;

    const float bx1 = boxes[roi * 4 + 0];
    const float by1 = boxes[roi * 4 + 1];
    const float bx2 = boxes[roi * 4 + 2];
    const float by2 = boxes[roi * 4 + 3];

    const float area = (bx2 - bx1) * (by2 - by1);
    const float s    = sqrtf(area);
    float lvlf = floorf(4.0f + log2f(s / 224.0f + 1e-6f));
    lvlf = fminf(fmaxf(lvlf, 2.0f), 5.0f);
    const int lvl = (int)lvlf - 2;   // 0..3

    const float scales[4] = {0.25f, 0.125f, 0.0625f, 0.03125f};
    const int   dims[4]   = {200, 100, 50, 25};
    const int   Ps[4]     = {40000, 10000, 2500, 625};
    const long  TO[4]     = {TOFF0, TOFF1, TOFF2, TOFF3};

    const float scale = scales[lvl];
    const int H = dims[lvl];
    const int W = H;
    const int img = img_ids[roi];
    const __half* __restrict__ tb = T + TO[lvl] + (size_t)img * (size_t)Ps[lvl] * NCH;

    const float x1 = bx1 * scale, y1 = by1 * scale;
    const float x2 = bx2 * scale, y2 = by2 * scale;
    const float roi_w = fmaxf(x2 - x1, 1.0f);
    const float roi_h = fmaxf(y2 - y1, 1.0f);
    const float bw = roi_w / (float)OUTD;
    const float bh = roi_h / (float)OUTD;

    __shared__ float4 s_yt[PD];
    __shared__ float4 s_xt[PD];
    __shared__ float  s_out[49 * 260];   // [bin][260]: x4-aligned writes, pad vs 256

    if (t < PD) {
        const int i = t >> 1, j = t & 1;
        const float yg = y1 + (float)i * bh + ((float)j + 0.5f) * bh * 0.5f;
        const float v = ((yg >= -1.0f) && (yg <= (float)H)) ? 1.0f : 0.0f;
        const float y = fminf(fmaxf(yg, 0.0f), (float)(H - 1));
        const int y0 = (int)floorf(y);
        const int y1i = min(y0 + 1, H - 1);
        const float ly = y - (float)y0;
        float4 r;
        r.x = __int_as_float(y0 * W);
        r.y = __int_as_float(y1i * W);
        r.z = (1.0f - ly) * v;
        r.w = ly * v;
        s_yt[t] = r;
    } else if (t < 2 * PD) {
        const int tt = t - PD;
        const int i = tt >> 1, j = tt & 1;
        const float xg = x1 + (float)i * bw + ((float)j + 0.5f) * bw * 0.5f;
        const float v = ((xg >= -1.0f) && (xg <= (float)W)) ? 1.0f : 0.0f;
        const float x = fminf(fmaxf(xg, 0.0f), (float)(W - 1));
        const int x0 = (int)floorf(x);
        const int x1i = min(x0 + 1, W - 1);
        const float lx = x - (float)x0;
        float4 r;
        r.x = __int_as_float(x0);
        r.y = __int_as_float(x1i);
        r.z = (1.0f - lx) * v;
        r.w = lx * v;
        s_xt[tt] = r;
    }
    __syncthreads();

    const int lane = t & 63;
    const int w    = t >> 6;
    const int c4   = lane * 4;

    for (int bin = w; bin < 49; bin += 4) {
        const int ph = (bin * 37) >> 8;        // exact /7 for bin<49
        const int pw = bin - ph * 7;
        float4 acc = {0.0f, 0.0f, 0.0f, 0.0f};
#pragma unroll
        for (int sy = 0; sy < 2; ++sy) {
            const float4 yt = s_yt[ph * 2 + sy];
            const int r0 = __float_as_int(yt.x);
            const int r1 = __float_as_int(yt.y);
            const float hy = yt.z, ly = yt.w;
#pragma unroll
            for (int sx = 0; sx < 2; ++sx) {
                const float4 xt = s_xt[pw * 2 + sx];
                const int xa = __float_as_int(xt.x);
                const int xb = __float_as_int(xt.y);
                const float hx = xt.z, lx = xt.w;
                const float w00 = hy * hx, w01 = hy * lx, w10 = ly * hx, w11 = ly * lx;

                const uint2 q00 = *(const uint2*)(tb + ((size_t)(r0 + xa) << 8) + c4);
                const uint2 q01 = *(const uint2*)(tb + ((size_t)(r0 + xb) << 8) + c4);
                const uint2 q10 = *(const uint2*)(tb + ((size_t)(r1 + xa) << 8) + c4);
                const uint2 q11 = *(const uint2*)(tb + ((size_t)(r1 + xb) << 8) + c4);

                const float2 a0 = __half22float2(*(const __half2*)&q00.x);
                const float2 a1 = __half22float2(*(const __half2*)&q00.y);
                const float2 b0 = __half22float2(*(const __half2*)&q01.x);
                const float2 b1 = __half22float2(*(const __half2*)&q01.y);
                const float2 c0 = __half22float2(*(const __half2*)&q10.x);
                const float2 c1 = __half22float2(*(const __half2*)&q10.y);
                const float2 d0 = __half22float2(*(const __half2*)&q11.x);
                const float2 d1 = __half22float2(*(const __half2*)&q11.y);

                acc.x += w00 * a0.x + w01 * b0.x + w10 * c0.x + w11 * d0.x;
                acc.y += w00 * a0.y + w01 * b0.y + w10 * c0.y + w11 * d0.y;
                acc.z += w00 * a1.x + w01 * b1.x + w10 * c1.x + w11 * d1.x;
                acc.w += w00 * a1.y + w01 * b1.y + w10 * c1.y + w11 * d1.y;
            }
        }
        float4 r;
        r.x = acc.x * 0.25f; r.y = acc.y * 0.25f;
        r.z = acc.z * 0.25f; r.w = acc.w * 0.25f;
        *(float4*)(&s_out[bin * 260 + c4]) = r;
    }
    __syncthreads();

    // coalesced output: 12544 contiguous floats per ROI
    float* __restrict__ outbase = out + (size_t)roi * (NCH * 49);
#pragma unroll
    for (int i = 0; i < 49; ++i) {
        const int e = t + i * 256;
        const int c = (int)(((unsigned)e * 21400u) >> 20);   // exact /49 for e<12544
        const int bin = e - c * 49;
        outbase[e] = s_out[bin * 260 + c];
    }
}

// ---------------- standalone sort (fallback path only) ----------------
__global__ __launch_bounds__(1024)
void sort_kernel(const float* __restrict__ boxes,
                 const int*   __restrict__ img_ids,
                 int* __restrict__ order, int N)
{
    __shared__ unsigned long long kv[1024];
    const int t = threadIdx.x;
    kv[t] = ((unsigned long long)roi_key(boxes, img_ids, t, N) << 32) | (unsigned)t;
    __syncthreads();
    for (int k = 2; k <= 1024; k <<= 1) {
        for (int j = k >> 1; j > 0; j >>= 1) {
            const int ixj = t ^ j;
            if (ixj > t) {
                const bool up = ((t & k) == 0);
                const unsigned long long a = kv[t], b = kv[ixj];
                if ((a > b) == up) { kv[t] = b; kv[ixj] = a; }
            }
            __syncthreads();
        }
    }
    if (t < N) order[t] = (int)(kv[t] & 0xFFFFFFFFu);
}

// ---------------- legacy pooler (round-0 verbatim, 101 us): ws-size fallback ----------------
#define LCHUNK 32
__global__ __launch_bounds__(256)
void pooler_legacy(const float* __restrict__ f0,
                   const float* __restrict__ f1,
                   const float* __restrict__ f2,
                   const float* __restrict__ f3,
                   const float* __restrict__ boxes,
                   const int*   __restrict__ img_ids,
                   const int*   __restrict__ order,
                   float* __restrict__ out, int N)
{
    int bx = blockIdx.x;
    int sidx;
    if ((N & 7) == 0) sidx = (bx & 7) * (N >> 3) + (bx >> 3);
    else              sidx = bx;
    const int roi = order[sidx];

    const int c0  = blockIdx.y * LCHUNK;
    const int t   = threadIdx.x;

    const float bx1 = boxes[roi * 4 + 0];
    const float by1 = boxes[roi * 4 + 1];
    const float bx2 = boxes[roi * 4 + 2];
    const float by2 = boxes[roi * 4 + 3];

    const float area = (bx2 - bx1) * (by2 - by1);
    const float s    = sqrtf(area);
    float lvlf = floorf(4.0f + log2f(s / 224.0f + 1e-6f));
    lvlf = fminf(fmaxf(lvlf, 2.0f), 5.0f);
    const int lvl = (int)lvlf - 2;

    const float scales[4] = {0.25f, 0.125f, 0.0625f, 0.03125f};
    const int   dims[4]   = {200, 100, 50, 25};
    const float* feats[4] = {f0, f1, f2, f3};

    const float scale = scales[lvl];
    const int H = dims[lvl];
    const int W = H;
    const int plane = H * W;

    const int img = img_ids[roi];
    const float* __restrict__ base0 =
        feats[lvl] + (size_t)img * NCH * (size_t)plane + (size_t)c0 * plane;

    const float x1 = bx1 * scale, y1 = by1 * scale;
    const float x2 = bx2 * scale, y2 = by2 * scale;
    const float roi_w = fmaxf(x2 - x1, 1.0f);
    const float roi_h = fmaxf(y2 - y1, 1.0f);
    const float bw = roi_w / (float)OUTD;
    const float bh = roi_h / (float)OUTD;

    __shared__ float4 s_yt[PD];
    __shared__ float4 s_xt[PD];
    __shared__ float4 s_xw[OUTD];
    __shared__ int    s_xf[OUTD];
    __shared__ int    s_ok[OUTD];

    if (t < PD) {
        const int i = t >> 1, j = t & 1;
        const float yg = y1 + (float)i * bh + ((float)j + 0.5f) * bh * 0.5f;
        const float v = ((yg >= -1.0f) && (yg <= (float)H)) ? 1.0f : 0.0f;
        const float y = fminf(fmaxf(yg, 0.0f), (float)(H - 1));
        const int y0 = (int)floorf(y);
        const int y1i = min(y0 + 1, H - 1);
        const float ly = y - (float)y0;
        float4 r;
        r.x = __int_as_float(y0 * W);
        r.y = __int_as_float(y1i * W);
        r.z = (1.0f - ly) * v;
        r.w = ly * v;
        s_yt[t] = r;
    } else if (t < 2 * PD) {
        const int tt = t - PD;
        const int i = tt >> 1, j = tt & 1;
        const float xg = x1 + (float)i * bw + ((float)j + 0.5f) * bw * 0.5f;
        const float v = ((xg >= -1.0f) && (xg <= (float)W)) ? 1.0f : 0.0f;
        const float x = fminf(fmaxf(xg, 0.0f), (float)(W - 1));
        const int x0 = (int)floorf(x);
        const float lx = x - (float)x0;
        const float hx = 1.0f - lx;
        const int edge = (x0 == W - 1);
        float4 r;
        r.x = __int_as_float(min(x0, W - 2));
        r.y = edge ? 0.0f   : hx * v;
        r.z = edge ? hx * v : lx * v;
        r.w = 0.0f;
        s_xt[tt] = r;
    } else if (t < 2 * PD + OUTD) {
        const int pw = t - 2 * PD;
        float w[4] = {0.0f, 0.0f, 0.0f, 0.0f};
        int ca[2], cb[2];
        float hxv[2], lxv[2];
#pragma unroll
        for (int j = 0; j < 2; ++j) {
            const float xg = x1 + (float)pw * bw + ((float)j + 0.5f) * bw * 0.5f;
            const float v = ((xg >= -1.0f) && (xg <= (float)W)) ? 1.0f : 0.0f;
            const float x = fminf(fmaxf(xg, 0.0f), (float)(W - 1));
            const int x0 = (int)floorf(x);
            const float lx = x - (float)x0;
            ca[j] = x0;
            cb[j] = min(x0 + 1, W - 1);
            hxv[j] = (1.0f - lx) * v;
            lxv[j] = lx * v;
        }
        const int ok = (cb[1] - ca[0]) <= 3;
        int xf = min(ca[0], W - 4);
        if (xf < 0) xf = 0;
        w[(ca[0] - xf) & 3] += hxv[0];
        w[(cb[0] - xf) & 3] += lxv[0];
        w[(ca[1] - xf) & 3] += hxv[1];
        w[(cb[1] - xf) & 3] += lxv[1];
        float4 wv; wv.x = w[0]; wv.y = w[1]; wv.z = w[2]; wv.w = w[3];
        s_xw[pw] = wv;
        s_xf[pw] = xf;
        s_ok[pw] = ok;
    }
    __syncthreads();

    const bool fused = s_ok[0] && s_ok[1] && s_ok[2] && s_ok[3] &&
                       s_ok[4] && s_ok[5] && s_ok[6];

    float* __restrict__ outbase = out + ((size_t)roi * NCH + c0) * 49;

    if (fused) {
        auto g4 = [&](const float* __restrict__ fp, int ph, int pw, float4* P) {
            const float4 yt0 = s_yt[2 * ph];
            const float4 yt1 = s_yt[2 * ph + 1];
            const int xf = s_xf[pw];
            P[0] = *(const float4*)(fp + __float_as_int(yt0.x) + xf);
            P[1] = *(const float4*)(fp + __float_as_int(yt0.y) + xf);
            P[2] = *(const float4*)(fp + __float_as_int(yt1.x) + xf);
            P[3] = *(const float4*)(fp + __float_as_int(yt1.y) + xf);
        };
        auto r4 = [&](int ph, int pw, const float4* P) -> float {
            const float4 w   = s_xw[pw];
            const float4 yt0 = s_yt[2 * ph];
            const float4 yt1 = s_yt[2 * ph + 1];
            const float d0 = w.x * P[0].x + w.y * P[0].y + w.z * P[0].z + w.w * P[0].w;
            const float d1 = w.x * P[1].x + w.y * P[1].y + w.z * P[1].z + w.w * P[1].w;
            const float d2 = w.x * P[2].x + w.y * P[2].y + w.z * P[2].z + w.w * P[2].w;
            const float d3 = w.x * P[3].x + w.y * P[3].y + w.z * P[3].z + w.w * P[3].w;
            return yt0.z * d0 + yt0.w * d1 + yt1.z * d2 + yt1.w * d3;
        };
        {
            int eA[4], phA[4], pwA[4];
            const float* fpA[4];
#pragma unroll
            for (int j = 0; j < 4; ++j) {
                const int e = t + j * 256;
                const int c = e / 49, bin = e - c * 49;
                phA[j] = bin / 7;
                pwA[j] = bin - phA[j] * 7;
                eA[j]  = e;
                fpA[j] = base0 + (size_t)c * plane;
            }
            float4 P[4][4];
#pragma unroll
            for (int j = 0; j < 4; ++j) g4(fpA[j], phA[j], pwA[j], P[j]);
            __builtin_amdgcn_sched_barrier(0);
#pragma unroll
            for (int j = 0; j < 4; ++j)
                outbase[eA[j]] = r4(phA[j], pwA[j], P[j]) * 0.25f;
        }
        {
            int eA[2], phA[2], pwA[2];
            const float* fpA[2];
#pragma unroll
            for (int j = 0; j < 2; ++j) {
                const int e = t + (4 + j) * 256;
                const int c = e / 49, bin = e - c * 49;
                phA[j] = bin / 7;
                pwA[j] = bin - phA[j] * 7;
                eA[j]  = e;
                fpA[j] = base0 + (size_t)c * plane;
            }
            float4 P[2][4];
#pragma unroll
            for (int j = 0; j < 2; ++j) g4(fpA[j], phA[j], pwA[j], P[j]);
            __builtin_amdgcn_sched_barrier(0);
#pragma unroll
            for (int j = 0; j < 2; ++j)
                outbase[eA[j]] = r4(phA[j], pwA[j], P[j]) * 0.25f;
        }
        if (t < 32) {
            const int e = 1536 + t;
            const int c = e / 49, bin = e - c * 49;
            const int ph = bin / 7, pw = bin - ph * 7;
            const float* fp = base0 + (size_t)c * plane;
            float4 P[4];
            g4(fp, ph, pw, P);
            outbase[e] = r4(ph, pw, P) * 0.25f;
        }
    } else {
        auto gather = [&](const float* __restrict__ fp, int ph, int pw, float2* P) {
#pragma unroll
            for (int sy = 0; sy < 2; ++sy) {
                const float4 yt = s_yt[ph * 2 + sy];
                const int ro0 = __float_as_int(yt.x);
                const int ro1 = __float_as_int(yt.y);
#pragma unroll
                for (int sx = 0; sx < 2; ++sx) {
                    const float4 xt = s_xt[pw * 2 + sx];
                    const int xa = __float_as_int(xt.x);
                    P[(sy * 2 + sx) * 2 + 0] = *(const float2*)(fp + ro0 + xa);
                    P[(sy * 2 + sx) * 2 + 1] = *(const float2*)(fp + ro1 + xa);
                }
            }
        };
        auto reduce = [&](int ph, int pw, const float2* P) -> float {
            float acc = 0.0f;
#pragma unroll
            for (int sy = 0; sy < 2; ++sy) {
                const float4 yt = s_yt[ph * 2 + sy];
                const float hy = yt.z, ly = yt.w;
#pragma unroll
                for (int sx = 0; sx < 2; ++sx) {
                    const float4 xt = s_xt[pw * 2 + sx];
                    const float wlo = xt.y, whi = xt.z;
                    const float2 p0 = P[(sy * 2 + sx) * 2 + 0];
                    const float2 p1 = P[(sy * 2 + sx) * 2 + 1];
                    acc += hy * (wlo * p0.x + whi * p0.y)
                         + ly * (wlo * p1.x + whi * p1.y);
                }
            }
            return acc;
        };
#pragma unroll
        for (int kk = 0; kk < 2; ++kk) {
            int eA[3], phA[3], pwA[3];
            const float* fpA[3];
#pragma unroll
            for (int j = 0; j < 3; ++j) {
                const int e = t + (kk * 3 + j) * 256;
                const int c = e / 49, bin = e - c * 49;
                phA[j] = bin / 7;
                pwA[j] = bin - phA[j] * 7;
                eA[j]  = e;
                fpA[j] = base0 + (size_t)c * plane;
            }
            float2 P[3][8];
#pragma unroll
            for (int j = 0; j < 3; ++j) gather(fpA[j], phA[j], pwA[j], P[j]);
            __builtin_amdgcn_sched_barrier(0);
#pragma unroll
            for (int j = 0; j < 3; ++j)
                outbase[eA[j]] = reduce(phA[j], pwA[j], P[j]) * 0.25f;
        }
        if (t < 32) {
            const int e = 1536 + t;
            const int c = e / 49, bin = e - c * 49;
            const int ph = bin / 7, pw = bin - ph * 7;
            const float* fp = base0 + (size_t)c * plane;
            float2 P[8];
            gather(fp, ph, pw, P);
            outbase[e] = reduce(ph, pw, P) * 0.25f;
        }
    }
}

extern "C" void kernel_launch(void* const* d_in, const int* in_sizes, int n_in,
                              void* d_out, int out_size, void* d_ws, size_t ws_size,
                              hipStream_t stream) {
    const float* f0    = (const float*)d_in[0];
    const float* f1    = (const float*)d_in[1];
    const float* f2    = (const float*)d_in[2];
    const float* f3    = (const float*)d_in[3];
    const float* boxes = (const float*)d_in[4];
    const int*   ids   = (const int*)d_in[5];
    float* out = (float*)d_out;
    int*   order = (int*)d_ws;

    const int N = in_sizes[4] / 4;   // number of ROIs (1000)

    const size_t need = (size_t)TBASE_BYTES + (size_t)TTOT * sizeof(__half);

    if (ws_size >= need && N <= 1024) {
        __half* T = (__half*)((char*)d_ws + TBASE_BYTES);
        prep_kernel<<<NB_TRANS + 1, 256, 0, stream>>>(f0, f1, f2, f3,
                                                      boxes, ids, order, T, N);
        pooler_t_kernel<<<N, 256, 0, stream>>>(T, boxes, ids, order, out, N);
    } else {
        sort_kernel<<<1, 1024, 0, stream>>>(boxes, ids, order, N);
        dim3 grid(N, NCH / LCHUNK);
        pooler_legacy<<<grid, 256, 0, stream>>>(f0, f1, f2, f3, boxes, ids, order, out, N);
    }
}

// Round 12
// 218.840 us; speedup vs baseline: 1.0611x; 1.0611x over previous
//
#include <hip/hip_runtime.h>
#include <hip/hip_fp16.h>

#define OUTD 7
#define PD 14             // 14 sample coords per axis
#define NCH 256

// ---- transposed buffer layout (HALF-element offsets), [lvl][img][P][C] ----
#define TOFF0 0
#define TOFF1 20480000    // + 2*40000*256
#define TOFF2 25600000    // + 2*10000*256
#define TOFF3 26880000    // + 2*2500*256
#define TTOT  27200000    // halfs (= 54.4 MB)
#define TBASE_BYTES 16384

// transpose tiling (round-10 proven: 54.4us): 64 p-rows x 256 ch, 512 threads.
// p-tiles/lvl: 625,157,40,10 -> 832/img -> 1664 transpose blocks + 1 sort block
#define NB_TRANS 1664

__device__ __forceinline__ unsigned int roi_key(const float* boxes,
                                                const int* img_ids, int e, int N)
{
    unsigned int key = 0xFFFFFFFFu;
    if (e < N) {
        const float bx1 = boxes[e * 4 + 0];
        const float by1 = boxes[e * 4 + 1];
        const float bx2 = boxes[e * 4 + 2];
        const float by2 = boxes[e * 4 + 3];
        const float area = (bx2 - bx1) * (by2 - by1);
        const float s = sqrtf(area);
        float lvlf = floorf(4.0f + log2f(s / 224.0f + 1e-6f));
        lvlf = fminf(fmaxf(lvlf, 2.0f), 5.0f);
        const int lvl = (int)lvlf - 2;
        const float scales[4] = {0.25f, 0.125f, 0.0625f, 0.03125f};
        const float sc = scales[lvl];
        int cx = (int)(0.5f * (bx1 + bx2) * sc);
        int cy = (int)(0.5f * (by1 + by2) * sc);
        cx = min(max(cx, 0), 127);
        cy = min(max(cy, 0), 127);
        unsigned int m = 0;
#pragma unroll
        for (int b = 0; b < 7; ++b)
            m |= ((cy >> b) & 1u) << (2 * b + 1) | ((cx >> b) & 1u) << (2 * b);
        key = ((((unsigned)lvl << 1) | (unsigned)img_ids[e]) << 14) | m;
    }
    return key;
}

// ---------------- fused prep: r10 transpose blocks + 1 sort block ----------------
// Round-11 lesson: 32-row tile halved read segments to 128B -> 1.5 TB/s, 78us
// (REGRESSION; 256B is the efficiency knee, r9: >=256B all equal). Revert to
// r10's 64x256 tile (256B reads / 512B writes, 54.4us measured). Sort (5us
// bitonic) fused as the last block -> hides under 1664 transpose blocks,
// saving the serial sort dispatch + launch gap.
__global__ __launch_bounds__(512)
void prep_kernel(const float* __restrict__ f0, const float* __restrict__ f1,
                 const float* __restrict__ f2, const float* __restrict__ f3,
                 const float* __restrict__ boxes,
                 const int*   __restrict__ img_ids,
                 int* __restrict__ order,
                 __half* __restrict__ T, int N)
{
    __shared__ __align__(16) float smbuf[64 * 260];   // 66560 B
    const int t = threadIdx.x;

    if (blockIdx.x == NB_TRANS) {
        // ==== sort path: bitonic over 1024 slots, 2 elems/thread ====
        unsigned long long* kv = (unsigned long long*)smbuf;
        for (int e = t; e < 1024; e += 512)
            kv[e] = ((unsigned long long)roi_key(boxes, img_ids, e, N) << 32)
                    | (unsigned)e;
        __syncthreads();
        for (int k = 2; k <= 1024; k <<= 1) {
            for (int j = k >> 1; j > 0; j >>= 1) {
                for (int i = t; i < 1024; i += 512) {
                    const int ixj = i ^ j;
                    if (ixj > i) {
                        const bool up = ((i & k) == 0);
                        const unsigned long long a = kv[i], b = kv[ixj];
                        if ((a > b) == up) { kv[i] = b; kv[ixj] = a; }
                    }
                }
                __syncthreads();
            }
        }
        for (int e = t; e < 1024; e += 512)
            if (e < N) order[e] = (int)(kv[e] & 0xFFFFFFFFu);
        return;
    }

    // ==== transpose path (r10 verbatim): [C][H][W] f32 -> [P][C] f16 ====
    int id = blockIdx.x;                           // 0..1663
    const int img = (id >= 832) ? 1 : 0; if (img) id -= 832;
    int lvl, pt;
    if (id < 625)      { lvl = 0; pt = id; }
    else if (id < 782) { lvl = 1; pt = id - 625; }
    else if (id < 822) { lvl = 2; pt = id - 782; }
    else               { lvl = 3; pt = id - 822; }

    const int  Ps[4]   = {40000, 10000, 2500, 625};
    const long TO[4]   = {TOFF0, TOFF1, TOFF2, TOFF3};
    const float* feats[4] = {f0, f1, f2, f3};
    const int P = Ps[lvl];
    const float* __restrict__ src = feats[lvl] + (size_t)img * NCH * (size_t)P;
    __half* __restrict__ dst = T + TO[lvl] + (size_t)img * (size_t)P * NCH;
    const int p0 = pt * 64;

    float (*tile)[260] = (float (*)[260])smbuf;    // stride 260 (1040B, 16B-aligned)

    // ---- phase 1: load 4 p-floats per channel (256B segments/wave-group) ----
    const int a  = t & 15;            // p4-group 0..15
    const int cg = t >> 4;            // 0..31
    const int p4 = a * 4;

#pragma unroll
    for (int i = 0; i < 8; ++i) {
        const int cs = cg + 32 * i;   // 0..255
        const float* sp = src + (size_t)cs * P + p0;
        float4 v;
        if (((P & 3) == 0) && (p0 + p4 + 3 < P)) {
            v = *(const float4*)(sp + p4);       // coalesced 16B, aligned
        } else {
            const int m = P - 1 - p0;            // clamp (edge tile / P=625)
            v.x = sp[min(p4 + 0, m)]; v.y = sp[min(p4 + 1, m)];
            v.z = sp[min(p4 + 2, m)]; v.w = sp[min(p4 + 3, m)];
        }
        tile[p4 + 0][cs] = v.x;
        tile[p4 + 1][cs] = v.y;
        tile[p4 + 2][cs] = v.z;
        tile[p4 + 3][cs] = v.w;
    }
    __syncthreads();

    // ---- phase 2: cvt fp16, write full [P][C] rows (512B/wave-instr) ----
    const int c4 = (t & 63) * 4;
    const int w  = t >> 6;            // 0..7
#pragma unroll
    for (int i = 0; i < 8; ++i) {
        const int p = w + 8 * i;      // 0..63
        if (p0 + p < P) {
            const __half2 h0 = __floats2half2_rn(tile[p][c4 + 0], tile[p][c4 + 1]);
            const __half2 h1 = __floats2half2_rn(tile[p][c4 + 2], tile[p][c4 + 3]);
            uint2 o;
            o.x = *(const unsigned int*)&h0;
            o.y = *(const unsigned int*)&h1;
            *(uint2*)(dst + (size_t)(p0 + p) * NCH + c4) = o;   // 8B aligned
        }
    }
}

// ---------------- pooler on transposed fp16 layout (r10: ~33us) ----------------
// Block = 1 ROI, 256 threads = 4 waves. Lane owns channels 4l..4l+3 (8B/lane,
// dwordx2): every tap load = 64 lanes x 8B = 512B contiguous, fully coalesced.
__global__ __launch_bounds__(256)
void pooler_t_kernel(const __half* __restrict__ T,
                     const float* __restrict__ boxes,
                     const int*   __restrict__ img_ids,
                     const int*   __restrict__ order,
                     float* __restrict__ out, int N)
{
    int bx = blockIdx.x;
    int sidx;
    if ((N & 7) == 0) sidx = (bx & 7) * (N >> 3) + (bx >> 3);  // XCD-contiguous
    else              sidx = bx;
    const int roi = order[sidx];
    const int t = threadIdx.x;

    const float bx1 = boxes[roi * 4 + 0];
    const float by1 = boxes[roi * 4 + 1];
    const float bx2 = boxes[roi * 4 + 2];
    const float by2 = boxes[roi * 4 + 3];

    const float area = (bx2 - bx1) * (by2 - by1);
    const float s    = sqrtf(area);
    float lvlf = floorf(4.0f + log2f(s / 224.0f + 1e-6f));
    lvlf = fminf(fmaxf(lvlf, 2.0f), 5.0f);
    const int lvl = (int)lvlf - 2;   // 0..3

    const float scales[4] = {0.25f, 0.125f, 0.0625f, 0.03125f};
    const int   dims[4]   = {200, 100, 50, 25};
    const int   Ps[4]     = {40000, 10000, 2500, 625};
    const long  TO[4]     = {TOFF0, TOFF1, TOFF2, TOFF3};

    const float scale = scales[lvl];
    const int H = dims[lvl];
    const int W = H;
    const int img = img_ids[roi];
    const __half* __restrict__ tb = T + TO[lvl] + (size_t)img * (size_t)Ps[lvl] * NCH;

    const float x1 = bx1 * scale, y1 = by1 * scale;
    const float x2 = bx2 * scale, y2 = by2 * scale;
    const float roi_w = fmaxf(x2 - x1, 1.0f);
    const float roi_h = fmaxf(y2 - y1, 1.0f);
    const float bw = roi_w / (float)OUTD;
    const float bh = roi_h / (float)OUTD;

    __shared__ float4 s_yt[PD];
    __shared__ float4 s_xt[PD];
    __shared__ float  s_out[49 * 260];   // [bin][260]: x4-aligned writes, pad vs 256

    if (t < PD) {
        const int i = t >> 1, j = t & 1;
        const float yg = y1 + (float)i * bh + ((float)j + 0.5f) * bh * 0.5f;
        const float v = ((yg >= -1.0f) && (yg <= (float)H)) ? 1.0f : 0.0f;
        const float y = fminf(fmaxf(yg, 0.0f), (float)(H - 1));
        const int y0 = (int)floorf(y);
        const int y1i = min(y0 + 1, H - 1);
        const float ly = y - (float)y0;
        float4 r;
        r.x = __int_as_float(y0 * W);
        r.y = __int_as_float(y1i * W);
        r.z = (1.0f - ly) * v;
        r.w = ly * v;
        s_yt[t] = r;
    } else if (t < 2 * PD) {
        const int tt = t - PD;
        const int i = tt >> 1, j = tt & 1;
        const float xg = x1 + (float)i * bw + ((float)j + 0.5f) * bw * 0.5f;
        const float v = ((xg >= -1.0f) && (xg <= (float)W)) ? 1.0f : 0.0f;
        const float x = fminf(fmaxf(xg, 0.0f), (float)(W - 1));
        const int x0 = (int)floorf(x);
        const int x1i = min(x0 + 1, W - 1);
        const float lx = x - (float)x0;
        float4 r;
        r.x = __int_as_float(x0);
        r.y = __int_as_float(x1i);
        r.z = (1.0f - lx) * v;
        r.w = lx * v;
        s_xt[tt] = r;
    }
    __syncthreads();

    const int lane = t & 63;
    const int w    = t >> 6;
    const int c4   = lane * 4;

    for (int bin = w; bin < 49; bin += 4) {
        const int ph = (bin * 37) >> 8;        // exact /7 for bin<49
        const int pw = bin - ph * 7;
        float4 acc = {0.0f, 0.0f, 0.0f, 0.0f};
#pragma unroll
        for (int sy = 0; sy < 2; ++sy) {
            const float4 yt = s_yt[ph * 2 + sy];
            const int r0 = __float_as_int(yt.x);
            const int r1 = __float_as_int(yt.y);
            const float hy = yt.z, ly = yt.w;
#pragma unroll
            for (int sx = 0; sx < 2; ++sx) {
                const float4 xt = s_xt[pw * 2 + sx];
                const int xa = __float_as_int(xt.x);
                const int xb = __float_as_int(xt.y);
                const float hx = xt.z, lx = xt.w;
                const float w00 = hy * hx, w01 = hy * lx, w10 = ly * hx, w11 = ly * lx;

                const uint2 q00 = *(const uint2*)(tb + ((size_t)(r0 + xa) << 8) + c4);
                const uint2 q01 = *(const uint2*)(tb + ((size_t)(r0 + xb) << 8) + c4);
                const uint2 q10 = *(const uint2*)(tb + ((size_t)(r1 + xa) << 8) + c4);
                const uint2 q11 = *(const uint2*)(tb + ((size_t)(r1 + xb) << 8) + c4);

                const float2 a0 = __half22float2(*(const __half2*)&q00.x);
                const float2 a1 = __half22float2(*(const __half2*)&q00.y);
                const float2 b0 = __half22float2(*(const __half2*)&q01.x);
                const float2 b1 = __half22float2(*(const __half2*)&q01.y);
                const float2 c0 = __half22float2(*(const __half2*)&q10.x);
                const float2 c1 = __half22float2(*(const __half2*)&q10.y);
                const float2 d0 = __half22float2(*(const __half2*)&q11.x);
                const float2 d1 = __half22float2(*(const __half2*)&q11.y);

                acc.x += w00 * a0.x + w01 * b0.x + w10 * c0.x + w11 * d0.x;
                acc.y += w00 * a0.y + w01 * b0.y + w10 * c0.y + w11 * d0.y;
                acc.z += w00 * a1.x + w01 * b1.x + w10 * c1.x + w11 * d1.x;
                acc.w += w00 * a1.y + w01 * b1.y + w10 * c1.y + w11 * d1.y;
            }
        }
        float4 r;
        r.x = acc.x * 0.25f; r.y = acc.y * 0.25f;
        r.z = acc.z * 0.25f; r.w = acc.w * 0.25f;
        *(float4*)(&s_out[bin * 260 + c4]) = r;
    }
    __syncthreads();

    // coalesced output: 12544 contiguous floats per ROI
    float* __restrict__ outbase = out + (size_t)roi * (NCH * 49);
#pragma unroll
    for (int i = 0; i < 49; ++i) {
        const int e = t + i * 256;
        const int c = (int)(((unsigned)e * 21400u) >> 20);   // exact /49 for e<12544
        const int bin = e - c * 49;
        outbase[e] = s_out[bin * 260 + c];
    }
}

// ---------------- standalone sort (fallback path only) ----------------
__global__ __launch_bounds__(1024)
void sort_kernel(const float* __restrict__ boxes,
                 const int*   __restrict__ img_ids,
                 int* __restrict__ order, int N)
{
    __shared__ unsigned long long kv[1024];
    const int t = threadIdx.x;
    kv[t] = ((unsigned long long)roi_key(boxes, img_ids, t, N) << 32) | (unsigned)t;
    __syncthreads();
    for (int k = 2; k <= 1024; k <<= 1) {
        for (int j = k >> 1; j > 0; j >>= 1) {
            const int ixj = t ^ j;
            if (ixj > t) {
                const bool up = ((t & k) == 0);
                const unsigned long long a = kv[t], b = kv[ixj];
                if ((a > b) == up) { kv[t] = b; kv[ixj] = a; }
            }
            __syncthreads();
        }
    }
    if (t < N) order[t] = (int)(kv[t] & 0xFFFFFFFFu);
}

// ---------------- legacy pooler (round-0 verbatim, 101 us): ws-size fallback ----------------
#define LCHUNK 32
__global__ __launch_bounds__(256)
void pooler_legacy(const float* __restrict__ f0,
                   const float* __restrict__ f1,
                   const float* __restrict__ f2,
                   const float* __restrict__ f3,
                   const float* __restrict__ boxes,
                   const int*   __restrict__ img_ids,
                   const int*   __restrict__ order,
                   float* __restrict__ out, int N)
{
    int bx = blockIdx.x;
    int sidx;
    if ((N & 7) == 0) sidx = (bx & 7) * (N >> 3) + (bx >> 3);
    else              sidx = bx;
    const int roi = order[sidx];

    const int c0  = blockIdx.y * LCHUNK;
    const int t   = threadIdx.x;

    const float bx1 = boxes[roi * 4 + 0];
    const float by1 = boxes[roi * 4 + 1];
    const float bx2 = boxes[roi * 4 + 2];
    const float by2 = boxes[roi * 4 + 3];

    const float area = (bx2 - bx1) * (by2 - by1);
    const float s    = sqrtf(area);
    float lvlf = floorf(4.0f + log2f(s / 224.0f + 1e-6f));
    lvlf = fminf(fmaxf(lvlf, 2.0f), 5.0f);
    const int lvl = (int)lvlf - 2;

    const float scales[4] = {0.25f, 0.125f, 0.0625f, 0.03125f};
    const int   dims[4]   = {200, 100, 50, 25};
    const float* feats[4] = {f0, f1, f2, f3};

    const float scale = scales[lvl];
    const int H = dims[lvl];
    const int W = H;
    const int plane = H * W;

    const int img = img_ids[roi];
    const float* __restrict__ base0 =
        feats[lvl] + (size_t)img * NCH * (size_t)plane + (size_t)c0 * plane;

    const float x1 = bx1 * scale, y1 = by1 * scale;
    const float x2 = bx2 * scale, y2 = by2 * scale;
    const float roi_w = fmaxf(x2 - x1, 1.0f);
    const float roi_h = fmaxf(y2 - y1, 1.0f);
    const float bw = roi_w / (float)OUTD;
    const float bh = roi_h / (float)OUTD;

    __shared__ float4 s_yt[PD];
    __shared__ float4 s_xt[PD];
    __shared__ float4 s_xw[OUTD];
    __shared__ int    s_xf[OUTD];
    __shared__ int    s_ok[OUTD];

    if (t < PD) {
        const int i = t >> 1, j = t & 1;
        const float yg = y1 + (float)i * bh + ((float)j + 0.5f) * bh * 0.5f;
        const float v = ((yg >= -1.0f) && (yg <= (float)H)) ? 1.0f : 0.0f;
        const float y = fminf(fmaxf(yg, 0.0f), (float)(H - 1));
        const int y0 = (int)floorf(y);
        const int y1i = min(y0 + 1, H - 1);
        const float ly = y - (float)y0;
        float4 r;
        r.x = __int_as_float(y0 * W);
        r.y = __int_as_float(y1i * W);
        r.z = (1.0f - ly) * v;
        r.w = ly * v;
        s_yt[t] = r;
    } else if (t < 2 * PD) {
        const int tt = t - PD;
        const int i = tt >> 1, j = tt & 1;
        const float xg = x1 + (float)i * bw + ((float)j + 0.5f) * bw * 0.5f;
        const float v = ((xg >= -1.0f) && (xg <= (float)W)) ? 1.0f : 0.0f;
        const float x = fminf(fmaxf(xg, 0.0f), (float)(W - 1));
        const int x0 = (int)floorf(x);
        const float lx = x - (float)x0;
        const float hx = 1.0f - lx;
        const int edge = (x0 == W - 1);
        float4 r;
        r.x = __int_as_float(min(x0, W - 2));
        r.y = edge ? 0.0f   : hx * v;
        r.z = edge ? hx * v : lx * v;
        r.w = 0.0f;
        s_xt[tt] = r;
    } else if (t < 2 * PD + OUTD) {
        const int pw = t - 2 * PD;
        float w[4] = {0.0f, 0.0f, 0.0f, 0.0f};
        int ca[2], cb[2];
        float hxv[2], lxv[2];
#pragma unroll
        for (int j = 0; j < 2; ++j) {
            const float xg = x1 + (float)pw * bw + ((float)j + 0.5f) * bw * 0.5f;
            const float v = ((xg >= -1.0f) && (xg <= (float)W)) ? 1.0f : 0.0f;
            const float x = fminf(fmaxf(xg, 0.0f), (float)(W - 1));
            const int x0 = (int)floorf(x);
            const float lx = x - (float)x0;
            ca[j] = x0;
            cb[j] = min(x0 + 1, W - 1);
            hxv[j] = (1.0f - lx) * v;
            lxv[j] = lx * v;
        }
        const int ok = (cb[1] - ca[0]) <= 3;
        int xf = min(ca[0], W - 4);
        if (xf < 0) xf = 0;
        w[(ca[0] - xf) & 3] += hxv[0];
        w[(cb[0] - xf) & 3] += lxv[0];
        w[(ca[1] - xf) & 3] += hxv[1];
        w[(cb[1] - xf) & 3] += lxv[1];
        float4 wv; wv.x = w[0]; wv.y = w[1]; wv.z = w[2]; wv.w = w[3];
        s_xw[pw] = wv;
        s_xf[pw] = xf;
        s_ok[pw] = ok;
    }
    __syncthreads();

    const bool fused = s_ok[0] && s_ok[1] && s_ok[2] && s_ok[3] &&
                       s_ok[4] && s_ok[5] && s_ok[6];

    float* __restrict__ outbase = out + ((size_t)roi * NCH + c0) * 49;

    if (fused) {
        auto g4 = [&](const float* __restrict__ fp, int ph, int pw, float4* P) {
            const float4 yt0 = s_yt[2 * ph];
            const float4 yt1 = s_yt[2 * ph + 1];
            const int xf = s_xf[pw];
            P[0] = *(const float4*)(fp + __float_as_int(yt0.x) + xf);
            P[1] = *(const float4*)(fp + __float_as_int(yt0.y) + xf);
            P[2] = *(const float4*)(fp + __float_as_int(yt1.x) + xf);
            P[3] = *(const float4*)(fp + __float_as_int(yt1.y) + xf);
        };
        auto r4 = [&](int ph, int pw, const float4* P) -> float {
            const float4 w   = s_xw[pw];
            const float4 yt0 = s_yt[2 * ph];
            const float4 yt1 = s_yt[2 * ph + 1];
            const float d0 = w.x * P[0].x + w.y * P[0].y + w.z * P[0].z + w.w * P[0].w;
            const float d1 = w.x * P[1].x + w.y * P[1].y + w.z * P[1].z + w.w * P[1].w;
            const float d2 = w.x * P[2].x + w.y * P[2].y + w.z * P[2].z + w.w * P[2].w;
            const float d3 = w.x * P[3].x + w.y * P[3].y + w.z * P[3].z + w.w * P[3].w;
            return yt0.z * d0 + yt0.w * d1 + yt1.z * d2 + yt1.w * d3;
        };
        {
            int eA[4], phA[4], pwA[4];
            const float* fpA[4];
#pragma unroll
            for (int j = 0; j < 4; ++j) {
                const int e = t + j * 256;
                const int c = e / 49, bin = e - c * 49;
                phA[j] = bin / 7;
                pwA[j] = bin - phA[j] * 7;
                eA[j]  = e;
                fpA[j] = base0 + (size_t)c * plane;
            }
            float4 P[4][4];
#pragma unroll
            for (int j = 0; j < 4; ++j) g4(fpA[j], phA[j], pwA[j], P[j]);
            __builtin_amdgcn_sched_barrier(0);
#pragma unroll
            for (int j = 0; j < 4; ++j)
                outbase[eA[j]] = r4(phA[j], pwA[j], P[j]) * 0.25f;
        }
        {
            int eA[2], phA[2], pwA[2];
            const float* fpA[2];
#pragma unroll
            for (int j = 0; j < 2; ++j) {
                const int e = t + (4 + j) * 256;
                const int c = e / 49, bin = e - c * 49;
                phA[j] = bin / 7;
                pwA[j] = bin - phA[j] * 7;
                eA[j]  = e;
                fpA[j] = base0 + (size_t)c * plane;
            }
            float4 P[2][4];
#pragma unroll
            for (int j = 0; j < 2; ++j) g4(fpA[j], phA[j], pwA[j], P[j]);
            __builtin_amdgcn_sched_barrier(0);
#pragma unroll
            for (int j = 0; j < 2; ++j)
                outbase[eA[j]] = r4(phA[j], pwA[j], P[j]) * 0.25f;
        }
        if (t < 32) {
            const int e = 1536 + t;
            const int c = e / 49, bin = e - c * 49;
            const int ph = bin / 7, pw = bin - ph * 7;
            const float* fp = base0 + (size_t)c * plane;
            float4 P[4];
            g4(fp, ph, pw, P);
            outbase[e] = r4(ph, pw, P) * 0.25f;
        }
    } else {
        auto gather = [&](const float* __restrict__ fp, int ph, int pw, float2* P) {
#pragma unroll
            for (int sy = 0; sy < 2; ++sy) {
                const float4 yt = s_yt[ph * 2 + sy];
                const int ro0 = __float_as_int(yt.x);
                const int ro1 = __float_as_int(yt.y);
#pragma unroll
                for (int sx = 0; sx < 2; ++sx) {
                    const float4 xt = s_xt[pw * 2 + sx];
                    const int xa = __float_as_int(xt.x);
                    P[(sy * 2 + sx) * 2 + 0] = *(const float2*)(fp + ro0 + xa);
                    P[(sy * 2 + sx) * 2 + 1] = *(const float2*)(fp + ro1 + xa);
                }
            }
        };
        auto reduce = [&](int ph, int pw, const float2* P) -> float {
            float acc = 0.0f;
#pragma unroll
            for (int sy = 0; sy < 2; ++sy) {
                const float4 yt = s_yt[ph * 2 + sy];
                const float hy = yt.z, ly = yt.w;
#pragma unroll
                for (int sx = 0; sx < 2; ++sx) {
                    const float4 xt = s_xt[pw * 2 + sx];
                    const float wlo = xt.y, whi = xt.z;
                    const float2 p0 = P[(sy * 2 + sx) * 2 + 0];
                    const float2 p1 = P[(sy * 2 + sx) * 2 + 1];
                    acc += hy * (wlo * p0.x + whi * p0.y)
                         + ly * (wlo * p1.x + whi * p1.y);
                }
            }
            return acc;
        };
#pragma unroll
        for (int kk = 0; kk < 2; ++kk) {
            int eA[3], phA[3], pwA[3];
            const float* fpA[3];
#pragma unroll
            for (int j = 0; j < 3; ++j) {
                const int e = t + (kk * 3 + j) * 256;
                const int c = e / 49, bin = e - c * 49;
                phA[j] = bin / 7;
                pwA[j] = bin - phA[j] * 7;
                eA[j]  = e;
                fpA[j] = base0 + (size_t)c * plane;
            }
            float2 P[3][8];
#pragma unroll
            for (int j = 0; j < 3; ++j) gather(fpA[j], phA[j], pwA[j], P[j]);
            __builtin_amdgcn_sched_barrier(0);
#pragma unroll
            for (int j = 0; j < 3; ++j)
                outbase[eA[j]] = reduce(phA[j], pwA[j], P[j]) * 0.25f;
        }
        if (t < 32) {
            const int e = 1536 + t;
            const int c = e / 49, bin = e - c * 49;
            const int ph = bin / 7, pw = bin - ph * 7;
            const float* fp = base0 + (size_t)c * plane;
            float2 P[8];
            gather(fp, ph, pw, P);
            outbase[e] = reduce(ph, pw, P) * 0.25f;
        }
    }
}

extern "C" void kernel_launch(void* const* d_in, const int* in_sizes, int n_in,
                              void* d_out, int out_size, void* d_ws, size_t ws_size,
                              hipStream_t stream) {
    const float* f0    = (const float*)d_in[0];
    const float* f1    = (const float*)d_in[1];
    const float* f2    = (const float*)d_in[2];
    const float* f3    = (const float*)d_in[3];
    const float* boxes = (const float*)d_in[4];
    const int*   ids   = (const int*)d_in[5];
    float* out = (float*)d_out;
    int*   order = (int*)d_ws;

    const int N = in_sizes[4] / 4;   // number of ROIs (1000)

    const size_t need = (size_t)TBASE_BYTES + (size_t)TTOT * sizeof(__half);

    if (ws_size >= need && N <= 1024) {
        __half* T = (__half*)((char*)d_ws + TBASE_BYTES);
        prep_kernel<<<NB_TRANS + 1, 512, 0, stream>>>(f0, f1, f2, f3,
                                                      boxes, ids, order, T, N);
        pooler_t_kernel<<<N, 256, 0, stream>>>(T, boxes, ids, order, out, N);
    } else {
        sort_kernel<<<1, 1024, 0, stream>>>(boxes, ids, order, N);
        dim3 grid(N, NCH / LCHUNK);
        pooler_legacy<<<grid, 256, 0, stream>>>(f0, f1, f2, f3, boxes, ids, order, out, N);
    }
}

// Round 13
// 208.181 us; speedup vs baseline: 1.1154x; 1.0512x over previous
//
#include <hip/hip_runtime.h>
#include <hip/hip_fp16.h>

#define OUTD 7
#define PD 14             // 14 sample coords per axis
#define NCH 256

// ---- transposed buffer layout (HALF-element offsets), [lvl][img][P][C] ----
#define TOFF0 0
#define TOFF1 20480000    // + 2*40000*256
#define TOFF2 25600000    // + 2*10000*256
#define TOFF3 26880000    // + 2*2500*256
#define TTOT  27200000    // halfs (= 54.4 MB)
#define TBASE_BYTES 16384

// transpose tiling (round-10 proven: 54.4us): 64 p-rows x 256 ch, 512 threads.
// p-tiles/lvl: 625,157,40,10 -> 832/img -> 1664 transpose blocks + 1 sort block
#define NB_TRANS 1664

__device__ __forceinline__ unsigned int roi_key(const float* boxes,
                                                const int* img_ids, int e, int N)
{
    unsigned int key = 0xFFFFFFFFu;
    if (e < N) {
        const float bx1 = boxes[e * 4 + 0];
        const float by1 = boxes[e * 4 + 1];
        const float bx2 = boxes[e * 4 + 2];
        const float by2 = boxes[e * 4 + 3];
        const float area = (bx2 - bx1) * (by2 - by1);
        const float s = sqrtf(area);
        float lvlf = floorf(4.0f + log2f(s / 224.0f + 1e-6f));
        lvlf = fminf(fmaxf(lvlf, 2.0f), 5.0f);
        const int lvl = (int)lvlf - 2;
        const float scales[4] = {0.25f, 0.125f, 0.0625f, 0.03125f};
        const float sc = scales[lvl];
        int cx = (int)(0.5f * (bx1 + bx2) * sc);
        int cy = (int)(0.5f * (by1 + by2) * sc);
        cx = min(max(cx, 0), 127);
        cy = min(max(cy, 0), 127);
        unsigned int m = 0;
#pragma unroll
        for (int b = 0; b < 7; ++b)
            m |= ((cy >> b) & 1u) << (2 * b + 1) | ((cx >> b) & 1u) << (2 * b);
        key = ((((unsigned)lvl << 1) | (unsigned)img_ids[e]) << 14) | m;
    }
    return key;
}

// ---------------- fused prep: 1 sort block (FIRST) + r10 transpose blocks ----
// Round-12 lesson: sort as the LAST block serialized at the kernel tail
// (prep 65us = 54.4 transpose + ~10 sort alone on 1 CU while grid drains).
// Fix: sort = block 0 -> starts at t~0, hides fully under the 54us
// transpose stream. Transpose blocks shift to id = blockIdx.x - 1.
__global__ __launch_bounds__(512)
void prep_kernel(const float* __restrict__ f0, const float* __restrict__ f1,
                 const float* __restrict__ f2, const float* __restrict__ f3,
                 const float* __restrict__ boxes,
                 const int*   __restrict__ img_ids,
                 int* __restrict__ order,
                 __half* __restrict__ T, int N)
{
    __shared__ __align__(16) float smbuf[64 * 260];   // 66560 B
    const int t = threadIdx.x;

    if (blockIdx.x == 0) {
        // ==== sort path: bitonic over 1024 slots, 2 elems/thread ====
        unsigned long long* kv = (unsigned long long*)smbuf;
        for (int e = t; e < 1024; e += 512)
            kv[e] = ((unsigned long long)roi_key(boxes, img_ids, e, N) << 32)
                    | (unsigned)e;
        __syncthreads();
        for (int k = 2; k <= 1024; k <<= 1) {
            for (int j = k >> 1; j > 0; j >>= 1) {
                for (int i = t; i < 1024; i += 512) {
                    const int ixj = i ^ j;
                    if (ixj > i) {
                        const bool up = ((i & k) == 0);
                        const unsigned long long a = kv[i], b = kv[ixj];
                        if ((a > b) == up) { kv[i] = b; kv[ixj] = a; }
                    }
                }
                __syncthreads();
            }
        }
        for (int e = t; e < 1024; e += 512)
            if (e < N) order[e] = (int)(kv[e] & 0xFFFFFFFFu);
        return;
    }

    // ==== transpose path (r10 verbatim): [C][H][W] f32 -> [P][C] f16 ====
    int id = blockIdx.x - 1;                       // 0..1663
    const int img = (id >= 832) ? 1 : 0; if (img) id -= 832;
    int lvl, pt;
    if (id < 625)      { lvl = 0; pt = id; }
    else if (id < 782) { lvl = 1; pt = id - 625; }
    else if (id < 822) { lvl = 2; pt = id - 782; }
    else               { lvl = 3; pt = id - 822; }

    const int  Ps[4]   = {40000, 10000, 2500, 625};
    const long TO[4]   = {TOFF0, TOFF1, TOFF2, TOFF3};
    const float* feats[4] = {f0, f1, f2, f3};
    const int P = Ps[lvl];
    const float* __restrict__ src = feats[lvl] + (size_t)img * NCH * (size_t)P;
    __half* __restrict__ dst = T + TO[lvl] + (size_t)img * (size_t)P * NCH;
    const int p0 = pt * 64;

    float (*tile)[260] = (float (*)[260])smbuf;    // stride 260 (1040B, 16B-aligned)

    // ---- phase 1: load 4 p-floats per channel (256B segments/wave-group) ----
    const int a  = t & 15;            // p4-group 0..15
    const int cg = t >> 4;            // 0..31
    const int p4 = a * 4;

#pragma unroll
    for (int i = 0; i < 8; ++i) {
        const int cs = cg + 32 * i;   // 0..255
        const float* sp = src + (size_t)cs * P + p0;
        float4 v;
        if (((P & 3) == 0) && (p0 + p4 + 3 < P)) {
            v = *(const float4*)(sp + p4);       // coalesced 16B, aligned
        } else {
            const int m = P - 1 - p0;            // clamp (edge tile / P=625)
            v.x = sp[min(p4 + 0, m)]; v.y = sp[min(p4 + 1, m)];
            v.z = sp[min(p4 + 2, m)]; v.w = sp[min(p4 + 3, m)];
        }
        tile[p4 + 0][cs] = v.x;
        tile[p4 + 1][cs] = v.y;
        tile[p4 + 2][cs] = v.z;
        tile[p4 + 3][cs] = v.w;
    }
    __syncthreads();

    // ---- phase 2: cvt fp16, write full [P][C] rows (512B/wave-instr) ----
    const int c4 = (t & 63) * 4;
    const int w  = t >> 6;            // 0..7
#pragma unroll
    for (int i = 0; i < 8; ++i) {
        const int p = w + 8 * i;      // 0..63
        if (p0 + p < P) {
            const __half2 h0 = __floats2half2_rn(tile[p][c4 + 0], tile[p][c4 + 1]);
            const __half2 h1 = __floats2half2_rn(tile[p][c4 + 2], tile[p][c4 + 3]);
            uint2 o;
            o.x = *(const unsigned int*)&h0;
            o.y = *(const unsigned int*)&h1;
            *(uint2*)(dst + (size_t)(p0 + p) * NCH + c4) = o;   // 8B aligned
        }
    }
}

// ---------------- pooler on transposed fp16 layout (r10: ~33us) ----------------
// Block = 1 ROI, 256 threads = 4 waves. Lane owns channels 4l..4l+3 (8B/lane,
// dwordx2): every tap load = 64 lanes x 8B = 512B contiguous, fully coalesced.
__global__ __launch_bounds__(256)
void pooler_t_kernel(const __half* __restrict__ T,
                     const float* __restrict__ boxes,
                     const int*   __restrict__ img_ids,
                     const int*   __restrict__ order,
                     float* __restrict__ out, int N)
{
    int bx = blockIdx.x;
    int sidx;
    if ((N & 7) == 0) sidx = (bx & 7) * (N >> 3) + (bx >> 3);  // XCD-contiguous
    else              sidx = bx;
    const int roi = order[sidx];
    const int t = threadIdx.x;

    const float bx1 = boxes[roi * 4 + 0];
    const float by1 = boxes[roi * 4 + 1];
    const float bx2 = boxes[roi * 4 + 2];
    const float by2 = boxes[roi * 4 + 3];

    const float area = (bx2 - bx1) * (by2 - by1);
    const float s    = sqrtf(area);
    float lvlf = floorf(4.0f + log2f(s / 224.0f + 1e-6f));
    lvlf = fminf(fmaxf(lvlf, 2.0f), 5.0f);
    const int lvl = (int)lvlf - 2;   // 0..3

    const float scales[4] = {0.25f, 0.125f, 0.0625f, 0.03125f};
    const int   dims[4]   = {200, 100, 50, 25};
    const int   Ps[4]     = {40000, 10000, 2500, 625};
    const long  TO[4]     = {TOFF0, TOFF1, TOFF2, TOFF3};

    const float scale = scales[lvl];
    const int H = dims[lvl];
    const int W = H;
    const int img = img_ids[roi];
    const __half* __restrict__ tb = T + TO[lvl] + (size_t)img * (size_t)Ps[lvl] * NCH;

    const float x1 = bx1 * scale, y1 = by1 * scale;
    const float x2 = bx2 * scale, y2 = by2 * scale;
    const float roi_w = fmaxf(x2 - x1, 1.0f);
    const float roi_h = fmaxf(y2 - y1, 1.0f);
    const float bw = roi_w / (float)OUTD;
    const float bh = roi_h / (float)OUTD;

    __shared__ float4 s_yt[PD];
    __shared__ float4 s_xt[PD];
    __shared__ float  s_out[49 * 260];   // [bin][260]: x4-aligned writes, pad vs 256

    if (t < PD) {
        const int i = t >> 1, j = t & 1;
        const float yg = y1 + (float)i * bh + ((float)j + 0.5f) * bh * 0.5f;
        const float v = ((yg >= -1.0f) && (yg <= (float)H)) ? 1.0f : 0.0f;
        const float y = fminf(fmaxf(yg, 0.0f), (float)(H - 1));
        const int y0 = (int)floorf(y);
        const int y1i = min(y0 + 1, H - 1);
        const float ly = y - (float)y0;
        float4 r;
        r.x = __int_as_float(y0 * W);
        r.y = __int_as_float(y1i * W);
        r.z = (1.0f - ly) * v;
        r.w = ly * v;
        s_yt[t] = r;
    } else if (t < 2 * PD) {
        const int tt = t - PD;
        const int i = tt >> 1, j = tt & 1;
        const float xg = x1 + (float)i * bw + ((float)j + 0.5f) * bw * 0.5f;
        const float v = ((xg >= -1.0f) && (xg <= (float)W)) ? 1.0f : 0.0f;
        const float x = fminf(fmaxf(xg, 0.0f), (float)(W - 1));
        const int x0 = (int)floorf(x);
        const int x1i = min(x0 + 1, W - 1);
        const float lx = x - (float)x0;
        float4 r;
        r.x = __int_as_float(x0);
        r.y = __int_as_float(x1i);
        r.z = (1.0f - lx) * v;
        r.w = lx * v;
        s_xt[tt] = r;
    }
    __syncthreads();

    const int lane = t & 63;
    const int w    = t >> 6;
    const int c4   = lane * 4;

    for (int bin = w; bin < 49; bin += 4) {
        const int ph = (bin * 37) >> 8;        // exact /7 for bin<49
        const int pw = bin - ph * 7;
        float4 acc = {0.0f, 0.0f, 0.0f, 0.0f};
#pragma unroll
        for (int sy = 0; sy < 2; ++sy) {
            const float4 yt = s_yt[ph * 2 + sy];
            const int r0 = __float_as_int(yt.x);
            const int r1 = __float_as_int(yt.y);
            const float hy = yt.z, ly = yt.w;
#pragma unroll
            for (int sx = 0; sx < 2; ++sx) {
                const float4 xt = s_xt[pw * 2 + sx];
                const int xa = __float_as_int(xt.x);
                const int xb = __float_as_int(xt.y);
                const float hx = xt.z, lx = xt.w;
                const float w00 = hy * hx, w01 = hy * lx, w10 = ly * hx, w11 = ly * lx;

                const uint2 q00 = *(const uint2*)(tb + ((size_t)(r0 + xa) << 8) + c4);
                const uint2 q01 = *(const uint2*)(tb + ((size_t)(r0 + xb) << 8) + c4);
                const uint2 q10 = *(const uint2*)(tb + ((size_t)(r1 + xa) << 8) + c4);
                const uint2 q11 = *(const uint2*)(tb + ((size_t)(r1 + xb) << 8) + c4);

                const float2 a0 = __half22float2(*(const __half2*)&q00.x);
                const float2 a1 = __half22float2(*(const __half2*)&q00.y);
                const float2 b0 = __half22float2(*(const __half2*)&q01.x);
                const float2 b1 = __half22float2(*(const __half2*)&q01.y);
                const float2 c0 = __half22float2(*(const __half2*)&q10.x);
                const float2 c1 = __half22float2(*(const __half2*)&q10.y);
                const float2 d0 = __half22float2(*(const __half2*)&q11.x);
                const float2 d1 = __half22float2(*(const __half2*)&q11.y);

                acc.x += w00 * a0.x + w01 * b0.x + w10 * c0.x + w11 * d0.x;
                acc.y += w00 * a0.y + w01 * b0.y + w10 * c0.y + w11 * d0.y;
                acc.z += w00 * a1.x + w01 * b1.x + w10 * c1.x + w11 * d1.x;
                acc.w += w00 * a1.y + w01 * b1.y + w10 * c1.y + w11 * d1.y;
            }
        }
        float4 r;
        r.x = acc.x * 0.25f; r.y = acc.y * 0.25f;
        r.z = acc.z * 0.25f; r.w = acc.w * 0.25f;
        *(float4*)(&s_out[bin * 260 + c4]) = r;
    }
    __syncthreads();

    // coalesced output: 12544 contiguous floats per ROI
    float* __restrict__ outbase = out + (size_t)roi * (NCH * 49);
#pragma unroll
    for (int i = 0; i < 49; ++i) {
        const int e = t + i * 256;
        const int c = (int)(((unsigned)e * 21400u) >> 20);   // exact /49 for e<12544
        const int bin = e - c * 49;
        outbase[e] = s_out[bin * 260 + c];
    }
}

// ---------------- standalone sort (fallback path only) ----------------
__global__ __launch_bounds__(1024)
void sort_kernel(const float* __restrict__ boxes,
                 const int*   __restrict__ img_ids,
                 int* __restrict__ order, int N)
{
    __shared__ unsigned long long kv[1024];
    const int t = threadIdx.x;
    kv[t] = ((unsigned long long)roi_key(boxes, img_ids, t, N) << 32) | (unsigned)t;
    __syncthreads();
    for (int k = 2; k <= 1024; k <<= 1) {
        for (int j = k >> 1; j > 0; j >>= 1) {
            const int ixj = t ^ j;
            if (ixj > t) {
                const bool up = ((t & k) == 0);
                const unsigned long long a = kv[t], b = kv[ixj];
                if ((a > b) == up) { kv[t] = b; kv[ixj] = a; }
            }
            __syncthreads();
        }
    }
    if (t < N) order[t] = (int)(kv[t] & 0xFFFFFFFFu);
}

// ---------------- legacy pooler (round-0 verbatim, 101 us): ws-size fallback ----------------
#define LCHUNK 32
__global__ __launch_bounds__(256)
void pooler_legacy(const float* __restrict__ f0,
                   const float* __restrict__ f1,
                   const float* __restrict__ f2,
                   const float* __restrict__ f3,
                   const float* __restrict__ boxes,
                   const int*   __restrict__ img_ids,
                   const int*   __restrict__ order,
                   float* __restrict__ out, int N)
{
    int bx = blockIdx.x;
    int sidx;
    if ((N & 7) == 0) sidx = (bx & 7) * (N >> 3) + (bx >> 3);
    else              sidx = bx;
    const int roi = order[sidx];

    const int c0  = blockIdx.y * LCHUNK;
    const int t   = threadIdx.x;

    const float bx1 = boxes[roi * 4 + 0];
    const float by1 = boxes[roi * 4 + 1];
    const float bx2 = boxes[roi * 4 + 2];
    const float by2 = boxes[roi * 4 + 3];

    const float area = (bx2 - bx1) * (by2 - by1);
    const float s    = sqrtf(area);
    float lvlf = floorf(4.0f + log2f(s / 224.0f + 1e-6f));
    lvlf = fminf(fmaxf(lvlf, 2.0f), 5.0f);
    const int lvl = (int)lvlf - 2;

    const float scales[4] = {0.25f, 0.125f, 0.0625f, 0.03125f};
    const int   dims[4]   = {200, 100, 50, 25};
    const float* feats[4] = {f0, f1, f2, f3};

    const float scale = scales[lvl];
    const int H = dims[lvl];
    const int W = H;
    const int plane = H * W;

    const int img = img_ids[roi];
    const float* __restrict__ base0 =
        feats[lvl] + (size_t)img * NCH * (size_t)plane + (size_t)c0 * plane;

    const float x1 = bx1 * scale, y1 = by1 * scale;
    const float x2 = bx2 * scale, y2 = by2 * scale;
    const float roi_w = fmaxf(x2 - x1, 1.0f);
    const float roi_h = fmaxf(y2 - y1, 1.0f);
    const float bw = roi_w / (float)OUTD;
    const float bh = roi_h / (float)OUTD;

    __shared__ float4 s_yt[PD];
    __shared__ float4 s_xt[PD];
    __shared__ float4 s_xw[OUTD];
    __shared__ int    s_xf[OUTD];
    __shared__ int    s_ok[OUTD];

    if (t < PD) {
        const int i = t >> 1, j = t & 1;
        const float yg = y1 + (float)i * bh + ((float)j + 0.5f) * bh * 0.5f;
        const float v = ((yg >= -1.0f) && (yg <= (float)H)) ? 1.0f : 0.0f;
        const float y = fminf(fmaxf(yg, 0.0f), (float)(H - 1));
        const int y0 = (int)floorf(y);
        const int y1i = min(y0 + 1, H - 1);
        const float ly = y - (float)y0;
        float4 r;
        r.x = __int_as_float(y0 * W);
        r.y = __int_as_float(y1i * W);
        r.z = (1.0f - ly) * v;
        r.w = ly * v;
        s_yt[t] = r;
    } else if (t < 2 * PD) {
        const int tt = t - PD;
        const int i = tt >> 1, j = tt & 1;
        const float xg = x1 + (float)i * bw + ((float)j + 0.5f) * bw * 0.5f;
        const float v = ((xg >= -1.0f) && (xg <= (float)W)) ? 1.0f : 0.0f;
        const float x = fminf(fmaxf(xg, 0.0f), (float)(W - 1));
        const int x0 = (int)floorf(x);
        const float lx = x - (float)x0;
        const float hx = 1.0f - lx;
        const int edge = (x0 == W - 1);
        float4 r;
        r.x = __int_as_float(min(x0, W - 2));
        r.y = edge ? 0.0f   : hx * v;
        r.z = edge ? hx * v : lx * v;
        r.w = 0.0f;
        s_xt[tt] = r;
    } else if (t < 2 * PD + OUTD) {
        const int pw = t - 2 * PD;
        float w[4] = {0.0f, 0.0f, 0.0f, 0.0f};
        int ca[2], cb[2];
        float hxv[2], lxv[2];
#pragma unroll
        for (int j = 0; j < 2; ++j) {
            const float xg = x1 + (float)pw * bw + ((float)j + 0.5f) * bw * 0.5f;
            const float v = ((xg >= -1.0f) && (xg <= (float)W)) ? 1.0f : 0.0f;
            const float x = fminf(fmaxf(xg, 0.0f), (float)(W - 1));
            const int x0 = (int)floorf(x);
            const float lx = x - (float)x0;
            ca[j] = x0;
            cb[j] = min(x0 + 1, W - 1);
            hxv[j] = (1.0f - lx) * v;
            lxv[j] = lx * v;
        }
        const int ok = (cb[1] - ca[0]) <= 3;
        int xf = min(ca[0], W - 4);
        if (xf < 0) xf = 0;
        w[(ca[0] - xf) & 3] += hxv[0];
        w[(cb[0] - xf) & 3] += lxv[0];
        w[(ca[1] - xf) & 3] += hxv[1];
        w[(cb[1] - xf) & 3] += lxv[1];
        float4 wv; wv.x = w[0]; wv.y = w[1]; wv.z = w[2]; wv.w = w[3];
        s_xw[pw] = wv;
        s_xf[pw] = xf;
        s_ok[pw] = ok;
    }
    __syncthreads();

    const bool fused = s_ok[0] && s_ok[1] && s_ok[2] && s_ok[3] &&
                       s_ok[4] && s_ok[5] && s_ok[6];

    float* __restrict__ outbase = out + ((size_t)roi * NCH + c0) * 49;

    if (fused) {
        auto g4 = [&](const float* __restrict__ fp, int ph, int pw, float4* P) {
            const float4 yt0 = s_yt[2 * ph];
            const float4 yt1 = s_yt[2 * ph + 1];
            const int xf = s_xf[pw];
            P[0] = *(const float4*)(fp + __float_as_int(yt0.x) + xf);
            P[1] = *(const float4*)(fp + __float_as_int(yt0.y) + xf);
            P[2] = *(const float4*)(fp + __float_as_int(yt1.x) + xf);
            P[3] = *(const float4*)(fp + __float_as_int(yt1.y) + xf);
        };
        auto r4 = [&](int ph, int pw, const float4* P) -> float {
            const float4 w   = s_xw[pw];
            const float4 yt0 = s_yt[2 * ph];
            const float4 yt1 = s_yt[2 * ph + 1];
            const float d0 = w.x * P[0].x + w.y * P[0].y + w.z * P[0].z + w.w * P[0].w;
            const float d1 = w.x * P[1].x + w.y * P[1].y + w.z * P[1].z + w.w * P[1].w;
            const float d2 = w.x * P[2].x + w.y * P[2].y + w.z * P[2].z + w.w * P[2].w;
            const float d3 = w.x * P[3].x + w.y * P[3].y + w.z * P[3].z + w.w * P[3].w;
            return yt0.z * d0 + yt0.w * d1 + yt1.z * d2 + yt1.w * d3;
        };
        {
            int eA[4], phA[4], pwA[4];
            const float* fpA[4];
#pragma unroll
            for (int j = 0; j < 4; ++j) {
                const int e = t + j * 256;
                const int c = e / 49, bin = e - c * 49;
                phA[j] = bin / 7;
                pwA[j] = bin - phA[j] * 7;
                eA[j]  = e;
                fpA[j] = base0 + (size_t)c * plane;
            }
            float4 P[4][4];
#pragma unroll
            for (int j = 0; j < 4; ++j) g4(fpA[j], phA[j], pwA[j], P[j]);
            __builtin_amdgcn_sched_barrier(0);
#pragma unroll
            for (int j = 0; j < 4; ++j)
                outbase[eA[j]] = r4(phA[j], pwA[j], P[j]) * 0.25f;
        }
        {
            int eA[2], phA[2], pwA[2];
            const float* fpA[2];
#pragma unroll
            for (int j = 0; j < 2; ++j) {
                const int e = t + (4 + j) * 256;
                const int c = e / 49, bin = e - c * 49;
                phA[j] = bin / 7;
                pwA[j] = bin - phA[j] * 7;
                eA[j]  = e;
                fpA[j] = base0 + (size_t)c * plane;
            }
            float4 P[2][4];
#pragma unroll
            for (int j = 0; j < 2; ++j) g4(fpA[j], phA[j], pwA[j], P[j]);
            __builtin_amdgcn_sched_barrier(0);
#pragma unroll
            for (int j = 0; j < 2; ++j)
                outbase[eA[j]] = r4(phA[j], pwA[j], P[j]) * 0.25f;
        }
        if (t < 32) {
            const int e = 1536 + t;
            const int c = e / 49, bin = e - c * 49;
            const int ph = bin / 7, pw = bin - ph * 7;
            const float* fp = base0 + (size_t)c * plane;
            float4 P[4];
            g4(fp, ph, pw, P);
            outbase[e] = r4(ph, pw, P) * 0.25f;
        }
    } else {
        auto gather = [&](const float* __restrict__ fp, int ph, int pw, float2* P) {
#pragma unroll
            for (int sy = 0; sy < 2; ++sy) {
                const float4 yt = s_yt[ph * 2 + sy];
                const int ro0 = __float_as_int(yt.x);
                const int ro1 = __float_as_int(yt.y);
#pragma unroll
                for (int sx = 0; sx < 2; ++sx) {
                    const float4 xt = s_xt[pw * 2 + sx];
                    const int xa = __float_as_int(xt.x);
                    P[(sy * 2 + sx) * 2 + 0] = *(const float2*)(fp + ro0 + xa);
                    P[(sy * 2 + sx) * 2 + 1] = *(const float2*)(fp + ro1 + xa);
                }
            }
        };
        auto reduce = [&](int ph, int pw, const float2* P) -> float {
            float acc = 0.0f;
#pragma unroll
            for (int sy = 0; sy < 2; ++sy) {
                const float4 yt = s_yt[ph * 2 + sy];
                const float hy = yt.z, ly = yt.w;
#pragma unroll
                for (int sx = 0; sx < 2; ++sx) {
                    const float4 xt = s_xt[pw * 2 + sx];
                    const float wlo = xt.y, whi = xt.z;
                    const float2 p0 = P[(sy * 2 + sx) * 2 + 0];
                    const float2 p1 = P[(sy * 2 + sx) * 2 + 1];
                    acc += hy * (wlo * p0.x + whi * p0.y)
                         + ly * (wlo * p1.x + whi * p1.y);
                }
            }
            return acc;
        };
#pragma unroll
        for (int kk = 0; kk < 2; ++kk) {
            int eA[3], phA[3], pwA[3];
            const float* fpA[3];
#pragma unroll
            for (int j = 0; j < 3; ++j) {
                const int e = t + (kk * 3 + j) * 256;
                const int c = e / 49, bin = e - c * 49;
                phA[j] = bin / 7;
                pwA[j] = bin - phA[j] * 7;
                eA[j]  = e;
                fpA[j] = base0 + (size_t)c * plane;
            }
            float2 P[3][8];
#pragma unroll
            for (int j = 0; j < 3; ++j) gather(fpA[j], phA[j], pwA[j], P[j]);
            __builtin_amdgcn_sched_barrier(0);
#pragma unroll
            for (int j = 0; j < 3; ++j)
                outbase[eA[j]] = reduce(phA[j], pwA[j], P[j]) * 0.25f;
        }
        if (t < 32) {
            const int e = 1536 + t;
            const int c = e / 49, bin = e - c * 49;
            const int ph = bin / 7, pw = bin - ph * 7;
            const float* fp = base0 + (size_t)c * plane;
            float2 P[8];
            gather(fp, ph, pw, P);
            outbase[e] = reduce(ph, pw, P) * 0.25f;
        }
    }
}

extern "C" void kernel_launch(void* const* d_in, const int* in_sizes, int n_in,
                              void* d_out, int out_size, void* d_ws, size_t ws_size,
                              hipStream_t stream) {
    const float* f0    = (const float*)d_in[0];
    const float* f1    = (const float*)d_in[1];
    const float* f2    = (const float*)d_in[2];
    const float* f3    = (const float*)d_in[3];
    const float* boxes = (const float*)d_in[4];
    const int*   ids   = (const int*)d_in[5];
    float* out = (float*)d_out;
    int*   order = (int*)d_ws;

    const int N = in_sizes[4] / 4;   // number of ROIs (1000)

    const size_t need = (size_t)TBASE_BYTES + (size_t)TTOT * sizeof(__half);

    if (ws_size >= need && N <= 1024) {
        __half* T = (__half*)((char*)d_ws + TBASE_BYTES);
        prep_kernel<<<NB_TRANS + 1, 512, 0, stream>>>(f0, f1, f2, f3,
                                                      boxes, ids, order, T, N);
        pooler_t_kernel<<<N, 256, 0, stream>>>(T, boxes, ids, order, out, N);
    } else {
        sort_kernel<<<1, 1024, 0, stream>>>(boxes, ids, order, N);
        dim3 grid(N, NCH / LCHUNK);
        pooler_legacy<<<grid, 256, 0, stream>>>(f0, f1, f2, f3, boxes, ids, order, out, N);
    }
}

// Round 14
// 208.089 us; speedup vs baseline: 1.1159x; 1.0004x over previous
//
#include <hip/hip_runtime.h>
#include <hip/hip_fp16.h>

#define OUTD 7
#define PD 14             // 14 sample coords per axis
#define NCH 256

// ---- transposed buffer layout (HALF-element offsets), [lvl][img][P][C] ----
#define TOFF0 0
#define TOFF1 20480000    // + 2*40000*256
#define TOFF2 25600000    // + 2*10000*256
#define TOFF3 26880000    // + 2*2500*256
#define TTOT  27200000    // halfs (= 54.4 MB)
#define TBASE_BYTES 16384

// transpose tiling (r14 probe): 128 p-rows x 256 ch, 512 threads, 133KB LDS.
// p-tiles/lvl: ceil(40000/128)=313, 79, 20, 5 -> 417/img -> 834 + 1 sort
#define NTILES_IMG 417
#define NB_TRANS   834

__device__ __forceinline__ unsigned int roi_key(const float* boxes,
                                                const int* img_ids, int e, int N)
{
    unsigned int key = 0xFFFFFFFFu;
    if (e < N) {
        const float bx1 = boxes[e * 4 + 0];
        const float by1 = boxes[e * 4 + 1];
        const float bx2 = boxes[e * 4 + 2];
        const float by2 = boxes[e * 4 + 3];
        const float area = (bx2 - bx1) * (by2 - by1);
        const float s = sqrtf(area);
        float lvlf = floorf(4.0f + log2f(s / 224.0f + 1e-6f));
        lvlf = fminf(fmaxf(lvlf, 2.0f), 5.0f);
        const int lvl = (int)lvlf - 2;
        const float scales[4] = {0.25f, 0.125f, 0.0625f, 0.03125f};
        const float sc = scales[lvl];
        int cx = (int)(0.5f * (bx1 + bx2) * sc);
        int cy = (int)(0.5f * (by1 + by2) * sc);
        cx = min(max(cx, 0), 127);
        cy = min(max(cy, 0), 127);
        unsigned int m = 0;
#pragma unroll
        for (int b = 0; b < 7; ++b)
            m |= ((cy >> b) & 1u) << (2 * b + 1) | ((cx >> b) & 1u) << (2 * b);
        key = ((((unsigned)lvl << 1) | (unsigned)img_ids[e]) << 14) | m;
    }
    return key;
}

// ---------------- fused prep: 1 sort block (FIRST) + transpose blocks --------
// r13: sort@block0 hides fully (65->56us, prediction matched). r14 probe:
// read-granularity. r9 proved WRITE granularity >=256B free; reads only
// probed at 128B (r11: 1.5TB/s BAD) and 256B (r7/r10/r13: ~2-2.9TB/s).
// This tile keeps r10's exact lane mapping (8-way LDS conflicts, proven
// hidden) but doubles the tile to 128p so each channel row is fetched as
// TWO ADJACENT 256B segments (512B page locality). Null -> declare roofline.
__global__ __launch_bounds__(512)
void prep_kernel(const float* __restrict__ f0, const float* __restrict__ f1,
                 const float* __restrict__ f2, const float* __restrict__ f3,
                 const float* __restrict__ boxes,
                 const int*   __restrict__ img_ids,
                 int* __restrict__ order,
                 __half* __restrict__ T, int N)
{
    __shared__ __align__(16) float smbuf[128 * 260];   // 133120 B
    const int t = threadIdx.x;

    if (blockIdx.x == 0) {
        // ==== sort path: bitonic over 1024 slots, 2 elems/thread ====
        unsigned long long* kv = (unsigned long long*)smbuf;
        for (int e = t; e < 1024; e += 512)
            kv[e] = ((unsigned long long)roi_key(boxes, img_ids, e, N) << 32)
                    | (unsigned)e;
        __syncthreads();
        for (int k = 2; k <= 1024; k <<= 1) {
            for (int j = k >> 1; j > 0; j >>= 1) {
                for (int i = t; i < 1024; i += 512) {
                    const int ixj = i ^ j;
                    if (ixj > i) {
                        const bool up = ((i & k) == 0);
                        const unsigned long long a = kv[i], b = kv[ixj];
                        if ((a > b) == up) { kv[i] = b; kv[ixj] = a; }
                    }
                }
                __syncthreads();
            }
        }
        for (int e = t; e < 1024; e += 512)
            if (e < N) order[e] = (int)(kv[e] & 0xFFFFFFFFu);
        return;
    }

    // ==== transpose path: [C][H][W] f32 -> [P][C] f16, 128p x 256c tile ====
    int id = blockIdx.x - 1;                       // 0..833
    const int img = (id >= NTILES_IMG) ? 1 : 0; if (img) id -= NTILES_IMG;
    int lvl, pt;
    if (id < 313)      { lvl = 0; pt = id; }
    else if (id < 392) { lvl = 1; pt = id - 313; }
    else if (id < 412) { lvl = 2; pt = id - 392; }
    else               { lvl = 3; pt = id - 412; }

    const int  Ps[4]   = {40000, 10000, 2500, 625};
    const long TO[4]   = {TOFF0, TOFF1, TOFF2, TOFF3};
    const float* feats[4] = {f0, f1, f2, f3};
    const int P = Ps[lvl];
    const float* __restrict__ src = feats[lvl] + (size_t)img * NCH * (size_t)P;
    __half* __restrict__ dst = T + TO[lvl] + (size_t)img * (size_t)P * NCH;
    const int p0 = pt * 128;

    float (*tile)[260] = (float (*)[260])smbuf;    // stride 260 (1040B, 16B-aligned)

    // ---- phase 1: two adjacent 256B segments per channel (512B locality) ----
    const int a  = t & 15;            // p4-group 0..15
    const int cg = t >> 4;            // 0..31
    const int p4 = a * 4;

    const bool fast = ((P & 3) == 0) && (p0 + 127 < P);   // whole tile in-range
#pragma unroll
    for (int i = 0; i < 8; ++i) {
        const int cs = cg + 32 * i;   // 0..255
        const float* sp = src + (size_t)cs * P + p0;
        float4 v0, v1;
        if (fast) {
            v0 = *(const float4*)(sp + p4);        // bytes [16a, 16a+16)
            v1 = *(const float4*)(sp + 64 + p4);   // bytes [256+16a, ...)
        } else {
            const int m = P - 1 - p0;              // clamp (edge tile / P=625)
            v0.x = sp[min(p4 + 0, m)];  v0.y = sp[min(p4 + 1, m)];
            v0.z = sp[min(p4 + 2, m)];  v0.w = sp[min(p4 + 3, m)];
            v1.x = sp[min(64 + p4 + 0, m)]; v1.y = sp[min(64 + p4 + 1, m)];
            v1.z = sp[min(64 + p4 + 2, m)]; v1.w = sp[min(64 + p4 + 3, m)];
        }
        tile[p4 + 0][cs] = v0.x;
        tile[p4 + 1][cs] = v0.y;
        tile[p4 + 2][cs] = v0.z;
        tile[p4 + 3][cs] = v0.w;
        tile[64 + p4 + 0][cs] = v1.x;
        tile[64 + p4 + 1][cs] = v1.y;
        tile[64 + p4 + 2][cs] = v1.z;
        tile[64 + p4 + 3][cs] = v1.w;
    }
    __syncthreads();

    // ---- phase 2: cvt fp16, write full [P][C] rows (512B/wave-instr) ----
    const int c4 = (t & 63) * 4;
    const int w  = t >> 6;            // 0..7
#pragma unroll
    for (int i = 0; i < 16; ++i) {
        const int p = w + 8 * i;      // 0..127
        if (p0 + p < P) {
            const __half2 h0 = __floats2half2_rn(tile[p][c4 + 0], tile[p][c4 + 1]);
            const __half2 h1 = __floats2half2_rn(tile[p][c4 + 2], tile[p][c4 + 3]);
            uint2 o;
            o.x = *(const unsigned int*)&h0;
            o.y = *(const unsigned int*)&h1;
            *(uint2*)(dst + (size_t)(p0 + p) * NCH + c4) = o;   // 8B aligned
        }
    }
}

// ---------------- pooler on transposed fp16 layout (r10: ~33us) ----------------
// Block = 1 ROI, 256 threads = 4 waves. Lane owns channels 4l..4l+3 (8B/lane,
// dwordx2): every tap load = 64 lanes x 8B = 512B contiguous, fully coalesced.
__global__ __launch_bounds__(256)
void pooler_t_kernel(const __half* __restrict__ T,
                     const float* __restrict__ boxes,
                     const int*   __restrict__ img_ids,
                     const int*   __restrict__ order,
                     float* __restrict__ out, int N)
{
    int bx = blockIdx.x;
    int sidx;
    if ((N & 7) == 0) sidx = (bx & 7) * (N >> 3) + (bx >> 3);  // XCD-contiguous
    else              sidx = bx;
    const int roi = order[sidx];
    const int t = threadIdx.x;

    const float bx1 = boxes[roi * 4 + 0];
    const float by1 = boxes[roi * 4 + 1];
    const float bx2 = boxes[roi * 4 + 2];
    const float by2 = boxes[roi * 4 + 3];

    const float area = (bx2 - bx1) * (by2 - by1);
    const float s    = sqrtf(area);
    float lvlf = floorf(4.0f + log2f(s / 224.0f + 1e-6f));
    lvlf = fminf(fmaxf(lvlf, 2.0f), 5.0f);
    const int lvl = (int)lvlf - 2;   // 0..3

    const float scales[4] = {0.25f, 0.125f, 0.0625f, 0.03125f};
    const int   dims[4]   = {200, 100, 50, 25};
    const int   Ps[4]     = {40000, 10000, 2500, 625};
    const long  TO[4]     = {TOFF0, TOFF1, TOFF2, TOFF3};

    const float scale = scales[lvl];
    const int H = dims[lvl];
    const int W = H;
    const int img = img_ids[roi];
    const __half* __restrict__ tb = T + TO[lvl] + (size_t)img * (size_t)Ps[lvl] * NCH;

    const float x1 = bx1 * scale, y1 = by1 * scale;
    const float x2 = bx2 * scale, y2 = by2 * scale;
    const float roi_w = fmaxf(x2 - x1, 1.0f);
    const float roi_h = fmaxf(y2 - y1, 1.0f);
    const float bw = roi_w / (float)OUTD;
    const float bh = roi_h / (float)OUTD;

    __shared__ float4 s_yt[PD];
    __shared__ float4 s_xt[PD];
    __shared__ float  s_out[49 * 260];   // [bin][260]: x4-aligned writes, pad vs 256

    if (t < PD) {
        const int i = t >> 1, j = t & 1;
        const float yg = y1 + (float)i * bh + ((float)j + 0.5f) * bh * 0.5f;
        const float v = ((yg >= -1.0f) && (yg <= (float)H)) ? 1.0f : 0.0f;
        const float y = fminf(fmaxf(yg, 0.0f), (float)(H - 1));
        const int y0 = (int)floorf(y);
        const int y1i = min(y0 + 1, H - 1);
        const float ly = y - (float)y0;
        float4 r;
        r.x = __int_as_float(y0 * W);
        r.y = __int_as_float(y1i * W);
        r.z = (1.0f - ly) * v;
        r.w = ly * v;
        s_yt[t] = r;
    } else if (t < 2 * PD) {
        const int tt = t - PD;
        const int i = tt >> 1, j = tt & 1;
        const float xg = x1 + (float)i * bw + ((float)j + 0.5f) * bw * 0.5f;
        const float v = ((xg >= -1.0f) && (xg <= (float)W)) ? 1.0f : 0.0f;
        const float x = fminf(fmaxf(xg, 0.0f), (float)(W - 1));
        const int x0 = (int)floorf(x);
        const int x1i = min(x0 + 1, W - 1);
        const float lx = x - (float)x0;
        float4 r;
        r.x = __int_as_float(x0);
        r.y = __int_as_float(x1i);
        r.z = (1.0f - lx) * v;
        r.w = lx * v;
        s_xt[tt] = r;
    }
    __syncthreads();

    const int lane = t & 63;
    const int w    = t >> 6;
    const int c4   = lane * 4;

    for (int bin = w; bin < 49; bin += 4) {
        const int ph = (bin * 37) >> 8;        // exact /7 for bin<49
        const int pw = bin - ph * 7;
        float4 acc = {0.0f, 0.0f, 0.0f, 0.0f};
#pragma unroll
        for (int sy = 0; sy < 2; ++sy) {
            const float4 yt = s_yt[ph * 2 + sy];
            const int r0 = __float_as_int(yt.x);
            const int r1 = __float_as_int(yt.y);
            const float hy = yt.z, ly = yt.w;
#pragma unroll
            for (int sx = 0; sx < 2; ++sx) {
                const float4 xt = s_xt[pw * 2 + sx];
                const int xa = __float_as_int(xt.x);
                const int xb = __float_as_int(xt.y);
                const float hx = xt.z, lx = xt.w;
                const float w00 = hy * hx, w01 = hy * lx, w10 = ly * hx, w11 = ly * lx;

                const uint2 q00 = *(const uint2*)(tb + ((size_t)(r0 + xa) << 8) + c4);
                const uint2 q01 = *(const uint2*)(tb + ((size_t)(r0 + xb) << 8) + c4);
                const uint2 q10 = *(const uint2*)(tb + ((size_t)(r1 + xa) << 8) + c4);
                const uint2 q11 = *(const uint2*)(tb + ((size_t)(r1 + xb) << 8) + c4);

                const float2 a0 = __half22float2(*(const __half2*)&q00.x);
                const float2 a1 = __half22float2(*(const __half2*)&q00.y);
                const float2 b0 = __half22float2(*(const __half2*)&q01.x);
                const float2 b1 = __half22float2(*(const __half2*)&q01.y);
                const float2 c0 = __half22float2(*(const __half2*)&q10.x);
                const float2 c1 = __half22float2(*(const __half2*)&q10.y);
                const float2 d0 = __half22float2(*(const __half2*)&q11.x);
                const float2 d1 = __half22float2(*(const __half2*)&q11.y);

                acc.x += w00 * a0.x + w01 * b0.x + w10 * c0.x + w11 * d0.x;
                acc.y += w00 * a0.y + w01 * b0.y + w10 * c0.y + w11 * d0.y;
                acc.z += w00 * a1.x + w01 * b1.x + w10 * c1.x + w11 * d1.x;
                acc.w += w00 * a1.y + w01 * b1.y + w10 * c1.y + w11 * d1.y;
            }
        }
        float4 r;
        r.x = acc.x * 0.25f; r.y = acc.y * 0.25f;
        r.z = acc.z * 0.25f; r.w = acc.w * 0.25f;
        *(float4*)(&s_out[bin * 260 + c4]) = r;
    }
    __syncthreads();

    // coalesced output: 12544 contiguous floats per ROI
    float* __restrict__ outbase = out + (size_t)roi * (NCH * 49);
#pragma unroll
    for (int i = 0; i < 49; ++i) {
        const int e = t + i * 256;
        const int c = (int)(((unsigned)e * 21400u) >> 20);   // exact /49 for e<12544
        const int bin = e - c * 49;
        outbase[e] = s_out[bin * 260 + c];
    }
}

// ---------------- standalone sort (fallback path only) ----------------
__global__ __launch_bounds__(1024)
void sort_kernel(const float* __restrict__ boxes,
                 const int*   __restrict__ img_ids,
                 int* __restrict__ order, int N)
{
    __shared__ unsigned long long kv[1024];
    const int t = threadIdx.x;
    kv[t] = ((unsigned long long)roi_key(boxes, img_ids, t, N) << 32) | (unsigned)t;
    __syncthreads();
    for (int k = 2; k <= 1024; k <<= 1) {
        for (int j = k >> 1; j > 0; j >>= 1) {
            const int ixj = t ^ j;
            if (ixj > t) {
                const bool up = ((t & k) == 0);
                const unsigned long long a = kv[t], b = kv[ixj];
                if ((a > b) == up) { kv[t] = b; kv[ixj] = a; }
            }
            __syncthreads();
        }
    }
    if (t < N) order[t] = (int)(kv[t] & 0xFFFFFFFFu);
}

// ---------------- legacy pooler (round-0 verbatim, 101 us): ws-size fallback ----------------
#define LCHUNK 32
__global__ __launch_bounds__(256)
void pooler_legacy(const float* __restrict__ f0,
                   const float* __restrict__ f1,
                   const float* __restrict__ f2,
                   const float* __restrict__ f3,
                   const float* __restrict__ boxes,
                   const int*   __restrict__ img_ids,
                   const int*   __restrict__ order,
                   float* __restrict__ out, int N)
{
    int bx = blockIdx.x;
    int sidx;
    if ((N & 7) == 0) sidx = (bx & 7) * (N >> 3) + (bx >> 3);
    else              sidx = bx;
    const int roi = order[sidx];

    const int c0  = blockIdx.y * LCHUNK;
    const int t   = threadIdx.x;

    const float bx1 = boxes[roi * 4 + 0];
    const float by1 = boxes[roi * 4 + 1];
    const float bx2 = boxes[roi * 4 + 2];
    const float by2 = boxes[roi * 4 + 3];

    const float area = (bx2 - bx1) * (by2 - by1);
    const float s    = sqrtf(area);
    float lvlf = floorf(4.0f + log2f(s / 224.0f + 1e-6f));
    lvlf = fminf(fmaxf(lvlf, 2.0f), 5.0f);
    const int lvl = (int)lvlf - 2;

    const float scales[4] = {0.25f, 0.125f, 0.0625f, 0.03125f};
    const int   dims[4]   = {200, 100, 50, 25};
    const float* feats[4] = {f0, f1, f2, f3};

    const float scale = scales[lvl];
    const int H = dims[lvl];
    const int W = H;
    const int plane = H * W;

    const int img = img_ids[roi];
    const float* __restrict__ base0 =
        feats[lvl] + (size_t)img * NCH * (size_t)plane + (size_t)c0 * plane;

    const float x1 = bx1 * scale, y1 = by1 * scale;
    const float x2 = bx2 * scale, y2 = by2 * scale;
    const float roi_w = fmaxf(x2 - x1, 1.0f);
    const float roi_h = fmaxf(y2 - y1, 1.0f);
    const float bw = roi_w / (float)OUTD;
    const float bh = roi_h / (float)OUTD;

    __shared__ float4 s_yt[PD];
    __shared__ float4 s_xt[PD];
    __shared__ float4 s_xw[OUTD];
    __shared__ int    s_xf[OUTD];
    __shared__ int    s_ok[OUTD];

    if (t < PD) {
        const int i = t >> 1, j = t & 1;
        const float yg = y1 + (float)i * bh + ((float)j + 0.5f) * bh * 0.5f;
        const float v = ((yg >= -1.0f) && (yg <= (float)H)) ? 1.0f : 0.0f;
        const float y = fminf(fmaxf(yg, 0.0f), (float)(H - 1));
        const int y0 = (int)floorf(y);
        const int y1i = min(y0 + 1, H - 1);
        const float ly = y - (float)y0;
        float4 r;
        r.x = __int_as_float(y0 * W);
        r.y = __int_as_float(y1i * W);
        r.z = (1.0f - ly) * v;
        r.w = ly * v;
        s_yt[t] = r;
    } else if (t < 2 * PD) {
        const int tt = t - PD;
        const int i = tt >> 1, j = tt & 1;
        const float xg = x1 + (float)i * bw + ((float)j + 0.5f) * bw * 0.5f;
        const float v = ((xg >= -1.0f) && (xg <= (float)W)) ? 1.0f : 0.0f;
        const float x = fminf(fmaxf(xg, 0.0f), (float)(W - 1));
        const int x0 = (int)floorf(x);
        const float lx = x - (float)x0;
        const float hx = 1.0f - lx;
        const int edge = (x0 == W - 1);
        float4 r;
        r.x = __int_as_float(min(x0, W - 2));
        r.y = edge ? 0.0f   : hx * v;
        r.z = edge ? hx * v : lx * v;
        r.w = 0.0f;
        s_xt[tt] = r;
    } else if (t < 2 * PD + OUTD) {
        const int pw = t - 2 * PD;
        float w[4] = {0.0f, 0.0f, 0.0f, 0.0f};
        int ca[2], cb[2];
        float hxv[2], lxv[2];
#pragma unroll
        for (int j = 0; j < 2; ++j) {
            const float xg = x1 + (float)pw * bw + ((float)j + 0.5f) * bw * 0.5f;
            const float v = ((xg >= -1.0f) && (xg <= (float)W)) ? 1.0f : 0.0f;
            const float x = fminf(fmaxf(xg, 0.0f), (float)(W - 1));
            const int x0 = (int)floorf(x);
            const float lx = x - (float)x0;
            ca[j] = x0;
            cb[j] = min(x0 + 1, W - 1);
            hxv[j] = (1.0f - lx) * v;
            lxv[j] = lx * v;
        }
        const int ok = (cb[1] - ca[0]) <= 3;
        int xf = min(ca[0], W - 4);
        if (xf < 0) xf = 0;
        w[(ca[0] - xf) & 3] += hxv[0];
        w[(cb[0] - xf) & 3] += lxv[0];
        w[(ca[1] - xf) & 3] += hxv[1];
        w[(cb[1] - xf) & 3] += lxv[1];
        float4 wv; wv.x = w[0]; wv.y = w[1]; wv.z = w[2]; wv.w = w[3];
        s_xw[pw] = wv;
        s_xf[pw] = xf;
        s_ok[pw] = ok;
    }
    __syncthreads();

    const bool fused = s_ok[0] && s_ok[1] && s_ok[2] && s_ok[3] &&
                       s_ok[4] && s_ok[5] && s_ok[6];

    float* __restrict__ outbase = out + ((size_t)roi * NCH + c0) * 49;

    if (fused) {
        auto g4 = [&](const float* __restrict__ fp, int ph, int pw, float4* P) {
            const float4 yt0 = s_yt[2 * ph];
            const float4 yt1 = s_yt[2 * ph + 1];
            const int xf = s_xf[pw];
            P[0] = *(const float4*)(fp + __float_as_int(yt0.x) + xf);
            P[1] = *(const float4*)(fp + __float_as_int(yt0.y) + xf);
            P[2] = *(const float4*)(fp + __float_as_int(yt1.x) + xf);
            P[3] = *(const float4*)(fp + __float_as_int(yt1.y) + xf);
        };
        auto r4 = [&](int ph, int pw, const float4* P) -> float {
            const float4 w   = s_xw[pw];
            const float4 yt0 = s_yt[2 * ph];
            const float4 yt1 = s_yt[2 * ph + 1];
            const float d0 = w.x * P[0].x + w.y * P[0].y + w.z * P[0].z + w.w * P[0].w;
            const float d1 = w.x * P[1].x + w.y * P[1].y + w.z * P[1].z + w.w * P[1].w;
            const float d2 = w.x * P[2].x + w.y * P[2].y + w.z * P[2].z + w.w * P[2].w;
            const float d3 = w.x * P[3].x + w.y * P[3].y + w.z * P[3].z + w.w * P[3].w;
            return yt0.z * d0 + yt0.w * d1 + yt1.z * d2 + yt1.w * d3;
        };
        {
            int eA[4], phA[4], pwA[4];
            const float* fpA[4];
#pragma unroll
            for (int j = 0; j < 4; ++j) {
                const int e = t + j * 256;
                const int c = e / 49, bin = e - c * 49;
                phA[j] = bin / 7;
                pwA[j] = bin - phA[j] * 7;
                eA[j]  = e;
                fpA[j] = base0 + (size_t)c * plane;
            }
            float4 P[4][4];
#pragma unroll
            for (int j = 0; j < 4; ++j) g4(fpA[j], phA[j], pwA[j], P[j]);
            __builtin_amdgcn_sched_barrier(0);
#pragma unroll
            for (int j = 0; j < 4; ++j)
                outbase[eA[j]] = r4(phA[j], pwA[j], P[j]) * 0.25f;
        }
        {
            int eA[2], phA[2], pwA[2];
            const float* fpA[2];
#pragma unroll
            for (int j = 0; j < 2; ++j) {
                const int e = t + (4 + j) * 256;
                const int c = e / 49, bin = e - c * 49;
                phA[j] = bin / 7;
                pwA[j] = bin - phA[j] * 7;
                eA[j]  = e;
                fpA[j] = base0 + (size_t)c * plane;
            }
            float4 P[2][4];
#pragma unroll
            for (int j = 0; j < 2; ++j) g4(fpA[j], phA[j], pwA[j], P[j]);
            __builtin_amdgcn_sched_barrier(0);
#pragma unroll
            for (int j = 0; j < 2; ++j)
                outbase[eA[j]] = r4(phA[j], pwA[j], P[j]) * 0.25f;
        }
        if (t < 32) {
            const int e = 1536 + t;
            const int c = e / 49, bin = e - c * 49;
            const int ph = bin / 7, pw = bin - ph * 7;
            const float* fp = base0 + (size_t)c * plane;
            float4 P[4];
            g4(fp, ph, pw, P);
            outbase[e] = r4(ph, pw, P) * 0.25f;
        }
    } else {
        auto gather = [&](const float* __restrict__ fp, int ph, int pw, float2* P) {
#pragma unroll
            for (int sy = 0; sy < 2; ++sy) {
                const float4 yt = s_yt[ph * 2 + sy];
                const int ro0 = __float_as_int(yt.x);
                const int ro1 = __float_as_int(yt.y);
#pragma unroll
                for (int sx = 0; sx < 2; ++sx) {
                    const float4 xt = s_xt[pw * 2 + sx];
                    const int xa = __float_as_int(xt.x);
                    P[(sy * 2 + sx) * 2 + 0] = *(const float2*)(fp + ro0 + xa);
                    P[(sy * 2 + sx) * 2 + 1] = *(const float2*)(fp + ro1 + xa);
                }
            }
        };
        auto reduce = [&](int ph, int pw, const float2* P) -> float {
            float acc = 0.0f;
#pragma unroll
            for (int sy = 0; sy < 2; ++sy) {
                const float4 yt = s_yt[ph * 2 + sy];
                const float hy = yt.z, ly = yt.w;
#pragma unroll
                for (int sx = 0; sx < 2; ++sx) {
                    const float4 xt = s_xt[pw * 2 + sx];
                    const float wlo = xt.y, whi = xt.z;
                    const float2 p0 = P[(sy * 2 + sx) * 2 + 0];
                    const float2 p1 = P[(sy * 2 + sx) * 2 + 1];
                    acc += hy * (wlo * p0.x + whi * p0.y)
                         + ly * (wlo * p1.x + whi * p1.y);
                }
            }
            return acc;
        };
#pragma unroll
        for (int kk = 0; kk < 2; ++kk) {
            int eA[3], phA[3], pwA[3];
            const float* fpA[3];
#pragma unroll
            for (int j = 0; j < 3; ++j) {
                const int e = t + (kk * 3 + j) * 256;
                const int c = e / 49, bin = e - c * 49;
                phA[j] = bin / 7;
                pwA[j] = bin - phA[j] * 7;
                eA[j]  = e;
                fpA[j] = base0 + (size_t)c * plane;
            }
            float2 P[3][8];
#pragma unroll
            for (int j = 0; j < 3; ++j) gather(fpA[j], phA[j], pwA[j], P[j]);
            __builtin_amdgcn_sched_barrier(0);
#pragma unroll
            for (int j = 0; j < 3; ++j)
                outbase[eA[j]] = reduce(phA[j], pwA[j], P[j]) * 0.25f;
        }
        if (t < 32) {
            const int e = 1536 + t;
            const int c = e / 49, bin = e - c * 49;
            const int ph = bin / 7, pw = bin - ph * 7;
            const float* fp = base0 + (size_t)c * plane;
            float2 P[8];
            gather(fp, ph, pw, P);
            outbase[e] = reduce(ph, pw, P) * 0.25f;
        }
    }
}

extern "C" void kernel_launch(void* const* d_in, const int* in_sizes, int n_in,
                              void* d_out, int out_size, void* d_ws, size_t ws_size,
                              hipStream_t stream) {
    const float* f0    = (const float*)d_in[0];
    const float* f1    = (const float*)d_in[1];
    const float* f2    = (const float*)d_in[2];
    const float* f3    = (const float*)d_in[3];
    const float* boxes = (const float*)d_in[4];
    const int*   ids   = (const int*)d_in[5];
    float* out = (float*)d_out;
    int*   order = (int*)d_ws;

    const int N = in_sizes[4] / 4;   // number of ROIs (1000)

    const size_t need = (size_t)TBASE_BYTES + (size_t)TTOT * sizeof(__half);

    if (ws_size >= need && N <= 1024) {
        __half* T = (__half*)((char*)d_ws + TBASE_BYTES);
        prep_kernel<<<NB_TRANS + 1, 512, 0, stream>>>(f0, f1, f2, f3,
                                                      boxes, ids, order, T, N);
        pooler_t_kernel<<<N, 256, 0, stream>>>(T, boxes, ids, order, out, N);
    } else {
        sort_kernel<<<1, 1024, 0, stream>>>(boxes, ids, order, N);
        dim3 grid(N, NCH / LCHUNK);
        pooler_legacy<<<grid, 256, 0, stream>>>(f0, f1, f2, f3, boxes, ids, order, out, N);
    }
}